// Round 1
// baseline (505.419 us; speedup 1.0000x reference)
//
#include <hip/hip_runtime.h>

// ---------------------------------------------------------------------------
// DiffAttention forward, bf16 MFMA pipeline.
// B=4 T=1024 C=1024 H=16 hs=64 dv=128.
// Stages:
//   1. cast x -> bf16; transpose-cast weights -> W^T[n][k] bf16
//   2. proj GEMM: proj[4096][6144] = xb @ wcat^T   (q1|q2|k1|k2|v)
//   3. transpose v slice -> vt[(b,h)][dim][token]
//   4. flash-style dual-softmax attention + subLN -> yln[4096][2048] bf16
//   5. out GEMM: out[4096][1024] fp32 = yln @ wc^T
// MFMA mappings (HW-verified per guide):
//   A frag: A[m=lane&15][k=quad*8+j], B frag: B^T[n=lane&15][k=quad*8+j]
//   C/D:    col=lane&15, row=quad*4+reg
// ---------------------------------------------------------------------------

#define T_SEQ 1024
#define BATCH 4
#define NH 16
#define DV 128
#define NPROJ 6144

typedef __bf16 bf16_t;
typedef __bf16 bf16x8 __attribute__((ext_vector_type(8)));
typedef __bf16 bf16x4 __attribute__((ext_vector_type(4)));
typedef float f32x4 __attribute__((ext_vector_type(4)));

#define LAMBDA_INIT 0.35550906759096928f
#define ONE_MINUS_LI 0.6444909324090307f
#define LOG2E 1.4426950408889634f

// ---------------- workspace layout (bytes) ----------------
static const size_t OFF_WCAT = 0;                                  // 6144x1024 bf16
static const size_t OFF_XB = OFF_WCAT + (size_t)6144 * 1024 * 2;   // 4096x1024 bf16
static const size_t OFF_WCT = OFF_XB + (size_t)4096 * 1024 * 2;    // 1024x2048 bf16
static const size_t OFF_PROJ = OFF_WCT + (size_t)2048 * 1024 * 2;  // 4096x6144 bf16
static const size_t OFF_VT = OFF_PROJ + (size_t)4096 * 6144 * 2;   // 64*128*1024 bf16
static const size_t OFF_YLN = OFF_VT + (size_t)64 * 128 * 1024 * 2;// 4096x2048 bf16
static const size_t OFF_LAM = OFF_YLN + (size_t)4096 * 2048 * 2;   // 16 f32

// ---------------- elementwise cast x -> bf16 ----------------
__global__ void __launch_bounds__(256) cast_x(const float* __restrict__ x,
                                              bf16_t* __restrict__ o) {
  const int i = (blockIdx.x * 256 + threadIdx.x) * 4;
  float4 v = *(const float4*)(x + i);
  bf16x4 r = {(bf16_t)v.x, (bf16_t)v.y, (bf16_t)v.z, (bf16_t)v.w};
  *(bf16x4*)(o + i) = r;
}

// ---------------- transpose-cast weight W[K][N] fp32 -> Wt[row0+n][k] bf16 ----
__global__ void __launch_bounds__(256) tcast_w(const float* __restrict__ W,
                                               bf16_t* __restrict__ Wt, int K,
                                               int N, int row0) {
  __shared__ float tile[32][33];
  const int k0 = blockIdx.x * 32, n0 = blockIdx.y * 32;
  const int tx = threadIdx.x & 31, ty = threadIdx.x >> 5;  // 32x8
#pragma unroll
  for (int i = 0; i < 32; i += 8)
    tile[ty + i][tx] = W[(long)(k0 + ty + i) * N + n0 + tx];
  __syncthreads();
#pragma unroll
  for (int i = 0; i < 32; i += 8)
    Wt[(long)(row0 + n0 + ty + i) * K + k0 + tx] = (bf16_t)tile[tx][ty + i];
}

// ---------------- per-head lambda ----------------
__global__ void lam_kernel(const float* __restrict__ lq1,
                           const float* __restrict__ lk1,
                           const float* __restrict__ lq2,
                           const float* __restrict__ lk2,
                           float* __restrict__ lam) {
  const int h = threadIdx.x;
  if (h < NH) {
    float d1 = 0.f, d2 = 0.f;
    for (int i = 0; i < 64; ++i) {
      d1 += lq1[h * 64 + i] * lk1[h * 64 + i];
      d2 += lq2[h * 64 + i] * lk2[h * 64 + i];
    }
    lam[h] = expf(d1) - expf(d2) + LAMBDA_INIT;
  }
}

// ---------------- GEMM: C[M][N] = A[M][K] @ Bt[N][K]^T ----------------
#define BM 128
#define BN 128
#define BK 32
#define BKP 40  // padded LDS row stride (elements)

template <typename OutT>
__global__ void __launch_bounds__(256) gemm_bt(const bf16_t* __restrict__ A,
                                               const bf16_t* __restrict__ Bt,
                                               OutT* __restrict__ C, int M,
                                               int N, int K) {
  __shared__ __align__(16) bf16_t As[BM * BKP];
  __shared__ __align__(16) bf16_t Bs[BN * BKP];
  const int tid = threadIdx.x;
  const int w = tid >> 6;
  const int lane = tid & 63;
  const int quad = lane >> 4, l16 = lane & 15;
  const int m0 = blockIdx.y * BM, n0 = blockIdx.x * BN;
  const int wm = (w >> 1) * 64, wn = (w & 1) * 64;
  const int srow = tid >> 2;            // 0..63
  const int scol = (tid & 3) * 8;       // 0,8,16,24

  const bf16_t* Ag0 = A + (long)(m0 + srow) * K + scol;
  const bf16_t* Ag1 = A + (long)(m0 + 64 + srow) * K + scol;
  const bf16_t* Bg0 = Bt + (long)(n0 + srow) * K + scol;
  const bf16_t* Bg1 = Bt + (long)(n0 + 64 + srow) * K + scol;

  f32x4 acc[4][4] = {};

  for (int k0 = 0; k0 < K; k0 += BK) {
    bf16x8 a0 = *(const bf16x8*)(Ag0 + k0);
    bf16x8 a1 = *(const bf16x8*)(Ag1 + k0);
    bf16x8 b0 = *(const bf16x8*)(Bg0 + k0);
    bf16x8 b1 = *(const bf16x8*)(Bg1 + k0);
    *(bf16x8*)(As + srow * BKP + scol) = a0;
    *(bf16x8*)(As + (64 + srow) * BKP + scol) = a1;
    *(bf16x8*)(Bs + srow * BKP + scol) = b0;
    *(bf16x8*)(Bs + (64 + srow) * BKP + scol) = b1;
    __syncthreads();
    bf16x8 af[4], bfr[4];
#pragma unroll
    for (int t = 0; t < 4; ++t) {
      af[t] = *(const bf16x8*)(As + (wm + t * 16 + l16) * BKP + quad * 8);
      bfr[t] = *(const bf16x8*)(Bs + (wn + t * 16 + l16) * BKP + quad * 8);
    }
#pragma unroll
    for (int mt = 0; mt < 4; ++mt)
#pragma unroll
      for (int nt = 0; nt < 4; ++nt)
        acc[mt][nt] = __builtin_amdgcn_mfma_f32_16x16x32_bf16(
            af[mt], bfr[nt], acc[mt][nt], 0, 0, 0);
    __syncthreads();
  }

#pragma unroll
  for (int mt = 0; mt < 4; ++mt)
#pragma unroll
    for (int nt = 0; nt < 4; ++nt) {
      const int col = n0 + wn + nt * 16 + l16;
#pragma unroll
      for (int i = 0; i < 4; ++i) {
        const int row = m0 + wm + mt * 16 + quad * 4 + i;
        C[(long)row * N + col] = (OutT)acc[mt][nt][i];
      }
    }
}

// ---------------- transpose v slice of proj -> vt[(b,h)][d][t] ----------------
__global__ void __launch_bounds__(256) transpose_v(const bf16_t* __restrict__ proj,
                                                   bf16_t* __restrict__ vt) {
  __shared__ bf16_t tile[32][34];
  const int bh = blockIdx.z;
  const int b = bh >> 4, h = bh & 15;
  const int t0 = blockIdx.x * 32, d0 = blockIdx.y * 32;
  const int tx = threadIdx.x & 31, ty = threadIdx.x >> 5;
  const bf16_t* src = proj + (long)(b * T_SEQ) * NPROJ + 4096 + h * 128;
#pragma unroll
  for (int i = 0; i < 32; i += 8)
    tile[ty + i][tx] = src[(long)(t0 + ty + i) * NPROJ + d0 + tx];
  __syncthreads();
  bf16_t* dst = vt + ((long)(b * NH + h) * DV) * T_SEQ;
#pragma unroll
  for (int i = 0; i < 32; i += 8)
    dst[(long)(d0 + ty + i) * T_SEQ + t0 + tx] = tile[tx][ty + i];
}

// ---------------- flash-style dual-softmax attention + subLN ----------------
// grid: (T/64, H, B), block 256 (4 waves, one 16-row q-tile per wave)
__global__ void __launch_bounds__(256) attn_kernel(const bf16_t* __restrict__ proj,
                                                   const bf16_t* __restrict__ vt,
                                                   const float* __restrict__ lamp,
                                                   bf16_t* __restrict__ yln) {
  const int qblk = (gridDim.x - 1) - blockIdx.x;  // heavy blocks first
  const int h = blockIdx.y;
  const int b = blockIdx.z;
  const int w = threadIdx.x >> 6, lane = threadIdx.x & 63;
  const int quad = lane >> 4, l16 = lane & 15;
  const int q0 = qblk * 64 + w * 16;
  const long bT = (long)b * T_SEQ;

  __shared__ __align__(16) bf16_t pbuf[4][2][16 * 40];

  const bf16_t* qrow = proj + (bT + q0 + l16) * (long)NPROJ + h * 64;
  bf16x8 aq1[2], aq2[2];
  aq1[0] = *(const bf16x8*)(qrow + quad * 8);
  aq1[1] = *(const bf16x8*)(qrow + 32 + quad * 8);
  aq2[0] = *(const bf16x8*)(qrow + 1024 + quad * 8);
  aq2[1] = *(const bf16x8*)(qrow + 1024 + 32 + quad * 8);

  f32x4 O1[8] = {}, O2[8] = {};
  float m1[4], l1[4], m2[4], l2[4];
#pragma unroll
  for (int i = 0; i < 4; ++i) {
    m1[i] = -3.0e38f;
    m2[i] = -3.0e38f;
    l1[i] = 0.f;
    l2[i] = 0.f;
  }

  const bf16_t* vbase = vt + ((long)(b * NH + h) * DV) * T_SEQ;
  bf16_t* pb1 = &pbuf[w][0][0];
  bf16_t* pb2 = &pbuf[w][1][0];
  const float sc = 0.125f * LOG2E;  // 1/sqrt(64) folded with log2(e)

  const int kend = q0 + 16;  // exclusive key bound
  for (int kt = 0; kt < kend; kt += 32) {
    // ---- S = Q K^T (both streams), 16x32 tile as two 16x16 C-frags ----
    f32x4 s1[2], s2[2];
#pragma unroll
    for (int c = 0; c < 2; ++c) {
      const bf16_t* krow = proj + (bT + kt + c * 16 + l16) * (long)NPROJ + h * 64;
      bf16x8 b10 = *(const bf16x8*)(krow + 2048 + quad * 8);
      bf16x8 b11 = *(const bf16x8*)(krow + 2048 + 32 + quad * 8);
      f32x4 z = {};
      z = __builtin_amdgcn_mfma_f32_16x16x32_bf16(aq1[0], b10, z, 0, 0, 0);
      z = __builtin_amdgcn_mfma_f32_16x16x32_bf16(aq1[1], b11, z, 0, 0, 0);
      s1[c] = z;
      bf16x8 b20 = *(const bf16x8*)(krow + 3072 + quad * 8);
      bf16x8 b21 = *(const bf16x8*)(krow + 3072 + 32 + quad * 8);
      f32x4 z2 = {};
      z2 = __builtin_amdgcn_mfma_f32_16x16x32_bf16(aq2[0], b20, z2, 0, 0, 0);
      z2 = __builtin_amdgcn_mfma_f32_16x16x32_bf16(aq2[1], b21, z2, 0, 0, 0);
      s2[c] = z2;
    }
    // ---- scale + causal mask (log2 domain) ----
    float t1[2][4], t2[2][4], mx1[4], mx2[4];
#pragma unroll
    for (int i = 0; i < 4; ++i) {
      mx1[i] = -3.0e38f;
      mx2[i] = -3.0e38f;
    }
#pragma unroll
    for (int c = 0; c < 2; ++c) {
      const int col = kt + c * 16 + l16;
#pragma unroll
      for (int i = 0; i < 4; ++i) {
        const int row = q0 + quad * 4 + i;
        float v1 = s1[c][i] * sc, v2 = s2[c][i] * sc;
        if (col > row) {
          v1 = -1e30f;
          v2 = -1e30f;
        }
        t1[c][i] = v1;
        t2[c][i] = v2;
        mx1[i] = fmaxf(mx1[i], v1);
        mx2[i] = fmaxf(mx2[i], v2);
      }
    }
    // row-max across the 16 lanes holding this row (xor<16 stays in group)
#pragma unroll
    for (int s = 1; s < 16; s <<= 1)
#pragma unroll
      for (int i = 0; i < 4; ++i) {
        mx1[i] = fmaxf(mx1[i], __shfl_xor(mx1[i], s));
        mx2[i] = fmaxf(mx2[i], __shfl_xor(mx2[i], s));
      }
    float al1[4], al2[4];
#pragma unroll
    for (int i = 0; i < 4; ++i) {
      float mn = fmaxf(m1[i], mx1[i]);
      al1[i] = exp2f(m1[i] - mn);
      m1[i] = mn;
      mn = fmaxf(m2[i], mx2[i]);
      al2[i] = exp2f(m2[i] - mn);
      m2[i] = mn;
    }
    // ---- P = exp2(t - m), bf16; stash to LDS for C->A layout transform ----
    float sum1[4] = {0, 0, 0, 0}, sum2[4] = {0, 0, 0, 0};
#pragma unroll
    for (int c = 0; c < 2; ++c)
#pragma unroll
      for (int i = 0; i < 4; ++i) {
        bf16_t p1 = (bf16_t)exp2f(t1[c][i] - m1[i]);
        bf16_t p2 = (bf16_t)exp2f(t2[c][i] - m2[i]);
        pb1[(quad * 4 + i) * 40 + c * 16 + l16] = p1;
        pb2[(quad * 4 + i) * 40 + c * 16 + l16] = p2;
        sum1[i] += (float)p1;
        sum2[i] += (float)p2;
      }
#pragma unroll
    for (int s = 1; s < 16; s <<= 1)
#pragma unroll
      for (int i = 0; i < 4; ++i) {
        sum1[i] += __shfl_xor(sum1[i], s);
        sum2[i] += __shfl_xor(sum2[i], s);
      }
#pragma unroll
    for (int i = 0; i < 4; ++i) {
      l1[i] = l1[i] * al1[i] + sum1[i];
      l2[i] = l2[i] * al2[i] + sum2[i];
    }
    // rescale O accumulators
#pragma unroll
    for (int f = 0; f < 8; ++f)
#pragma unroll
      for (int i = 0; i < 4; ++i) {
        O1[f][i] *= al1[i];
        O2[f][i] *= al2[i];
      }
    __asm__ volatile("s_waitcnt lgkmcnt(0)" ::: "memory");
    bf16x8 ap1 = *(const bf16x8*)(pb1 + l16 * 40 + quad * 8);
    bf16x8 ap2 = *(const bf16x8*)(pb2 + l16 * 40 + quad * 8);
    // ---- PV: O += P @ V (V frags shared between streams) ----
    const bf16_t* vp = vbase + kt + quad * 8;
#pragma unroll
    for (int f = 0; f < 8; ++f) {
      bf16x8 bv = *(const bf16x8*)(vp + (long)(f * 16 + l16) * T_SEQ);
      O1[f] = __builtin_amdgcn_mfma_f32_16x16x32_bf16(ap1, bv, O1[f], 0, 0, 0);
      O2[f] = __builtin_amdgcn_mfma_f32_16x16x32_bf16(ap2, bv, O2[f], 0, 0, 0);
    }
  }

  // ---- combine streams, subLN over 128 dims, scale, store bf16 ----
  const float lam = lamp[h];
  float inv1[4], inv2[4];
#pragma unroll
  for (int i = 0; i < 4; ++i) {
    inv1[i] = 1.0f / l1[i];
    inv2[i] = lam / l2[i];
  }
  float sm[4] = {0, 0, 0, 0}, sq[4] = {0, 0, 0, 0};
#pragma unroll
  for (int f = 0; f < 8; ++f)
#pragma unroll
    for (int i = 0; i < 4; ++i) {
      float y = O1[f][i] * inv1[i] - O2[f][i] * inv2[i];
      O1[f][i] = y;
      sm[i] += y;
      sq[i] += y * y;
    }
#pragma unroll
  for (int s = 1; s < 16; s <<= 1)
#pragma unroll
    for (int i = 0; i < 4; ++i) {
      sm[i] += __shfl_xor(sm[i], s);
      sq[i] += __shfl_xor(sq[i], s);
    }
  float mu[4], rs[4];
#pragma unroll
  for (int i = 0; i < 4; ++i) {
    mu[i] = sm[i] * (1.0f / 128.0f);
    float var = sq[i] * (1.0f / 128.0f) - mu[i] * mu[i];
    rs[i] = rsqrtf(var + 1e-5f) * ONE_MINUS_LI;
  }
#pragma unroll
  for (int i = 0; i < 4; ++i) {
    bf16_t* dst = yln + (bT + q0 + quad * 4 + i) * (long)2048 + h * 128 + l16;
#pragma unroll
    for (int f = 0; f < 8; ++f)
      dst[f * 16] = (bf16_t)((O1[f][i] - mu[i]) * rs[i]);
  }
}

// ---------------------------------------------------------------------------
extern "C" void kernel_launch(void* const* d_in, const int* in_sizes, int n_in,
                              void* d_out, int out_size, void* d_ws,
                              size_t ws_size, hipStream_t stream) {
  const float* x = (const float*)d_in[0];
  const float* Wq1 = (const float*)d_in[1];
  const float* Wq2 = (const float*)d_in[2];
  const float* Wk1 = (const float*)d_in[3];
  const float* Wk2 = (const float*)d_in[4];
  const float* Wv = (const float*)d_in[5];
  const float* Wc = (const float*)d_in[6];
  const float* lq1 = (const float*)d_in[7];
  const float* lk1 = (const float*)d_in[8];
  const float* lq2 = (const float*)d_in[9];
  const float* lk2 = (const float*)d_in[10];
  float* out = (float*)d_out;

  char* ws = (char*)d_ws;
  bf16_t* wcat = (bf16_t*)(ws + OFF_WCAT);
  bf16_t* xb = (bf16_t*)(ws + OFF_XB);
  bf16_t* wct = (bf16_t*)(ws + OFF_WCT);
  bf16_t* projb = (bf16_t*)(ws + OFF_PROJ);
  bf16_t* vtb = (bf16_t*)(ws + OFF_VT);
  bf16_t* ylnb = (bf16_t*)(ws + OFF_YLN);
  float* lamp = (float*)(ws + OFF_LAM);

  cast_x<<<4096, 256, 0, stream>>>(x, xb);
  tcast_w<<<dim3(32, 32), 256, 0, stream>>>(Wq1, wcat, 1024, 1024, 0);
  tcast_w<<<dim3(32, 32), 256, 0, stream>>>(Wq2, wcat, 1024, 1024, 1024);
  tcast_w<<<dim3(32, 32), 256, 0, stream>>>(Wk1, wcat, 1024, 1024, 2048);
  tcast_w<<<dim3(32, 32), 256, 0, stream>>>(Wk2, wcat, 1024, 1024, 3072);
  tcast_w<<<dim3(32, 64), 256, 0, stream>>>(Wv, wcat, 1024, 2048, 4096);
  tcast_w<<<dim3(64, 32), 256, 0, stream>>>(Wc, wct, 2048, 1024, 0);
  lam_kernel<<<1, 64, 0, stream>>>(lq1, lk1, lq2, lk2, lamp);

  // proj = xb @ wcat^T : M=4096 N=6144 K=1024
  gemm_bt<bf16_t><<<dim3(48, 32), 256, 0, stream>>>(xb, wcat, projb, 4096, 6144, 1024);
  transpose_v<<<dim3(32, 4, 64), 256, 0, stream>>>(projb, vtb);
  attn_kernel<<<dim3(16, 16, 4), 256, 0, stream>>>(projb, vtb, lamp, ylnb);
  // out = yln @ wc^T : M=4096 N=1024 K=2048
  gemm_bt<float><<<dim3(8, 32), 256, 0, stream>>>(ylnb, wct, out, 4096, 1024, 2048);
}

// Round 3
// 461.700 us; speedup vs baseline: 1.0947x; 1.0947x over previous
//
#include <hip/hip_runtime.h>

// ---------------------------------------------------------------------------
// DiffAttention forward, bf16 MFMA pipeline.  B=4 T=1024 C=1024 H=16 hs=64 dv=128.
//   1. cast x -> bf16; transpose-cast weights -> W^T[n][k] bf16
//   2. proj GEMM (m97-style global_load_lds): proj[4096][6144] = xb @ wcat^T
//   3. transpose v slice -> vt[(b,h)][dim][token]
//   4. attention: cooperative reg->LDS staging (prefetch-pipelined), dual
//      online softmax, PV via MFMA, fused subLN -> yln[4096][2048] bf16
//   5. out GEMM: out[4096][1024] fp32 = yln @ wc^T
// MFMA mappings (HW-verified): A[m=lane&15][k=quad*8+j]; B^T[n=lane&15][k=...]
// C/D: col=lane&15, row=quad*4+reg.
// NOTE: GLDS (async LDS-DMA) is used ONLY in the gemm (m97-verified shape).
// attn uses plain reg round-trip staging: R2's GLDS-in-attn produced sporadic
// stale-tile reads (absmax 0.086 vs 0.023) — suspected LDS-DMA waitcnt
// tracking miss across the guarded multi-LDS-object control flow.
// ---------------------------------------------------------------------------

#define T_SEQ 1024
#define NH 16
#define DV 128
#define NPROJ 6144

typedef __bf16 bf16_t;
typedef __bf16 bf16x8 __attribute__((ext_vector_type(8)));
typedef __bf16 bf16x4 __attribute__((ext_vector_type(4)));
typedef float f32x4 __attribute__((ext_vector_type(4)));

#define LAMBDA_INIT 0.35550906759096928f
#define ONE_MINUS_LI 0.6444909324090307f
#define LOG2E 1.4426950408889634f

// async global->LDS, 16B/lane (gemm only).
#define GLDS(g, l)                                                            \
  __builtin_amdgcn_global_load_lds(                                           \
      (const __attribute__((address_space(1))) void*)(g),                     \
      (__attribute__((address_space(3))) void*)(l), 16, 0, 0)

// ---------------- workspace layout (bytes) ----------------
static const size_t OFF_WCAT = 0;                                  // 6144x1024 bf16
static const size_t OFF_XB = OFF_WCAT + (size_t)6144 * 1024 * 2;   // 4096x1024 bf16
static const size_t OFF_WCT = OFF_XB + (size_t)4096 * 1024 * 2;    // 1024x2048 bf16
static const size_t OFF_PROJ = OFF_WCT + (size_t)2048 * 1024 * 2;  // 4096x6144 bf16
static const size_t OFF_VT = OFF_PROJ + (size_t)4096 * 6144 * 2;   // 64*128*1024 bf16
static const size_t OFF_YLN = OFF_VT + (size_t)64 * 128 * 1024 * 2;// 4096x2048 bf16
static const size_t OFF_LAM = OFF_YLN + (size_t)4096 * 2048 * 2;   // 16 f32

// ---------------- elementwise cast x -> bf16 ----------------
__global__ void __launch_bounds__(256) cast_x(const float* __restrict__ x,
                                              bf16_t* __restrict__ o) {
  const int i = (blockIdx.x * 256 + threadIdx.x) * 4;
  float4 v = *(const float4*)(x + i);
  bf16x4 r = {(bf16_t)v.x, (bf16_t)v.y, (bf16_t)v.z, (bf16_t)v.w};
  *(bf16x4*)(o + i) = r;
}

// ---------------- transpose-cast weight W[K][N] fp32 -> Wt[row0+n][k] bf16 ----
__global__ void __launch_bounds__(256) tcast_w(const float* __restrict__ W,
                                               bf16_t* __restrict__ Wt, int K,
                                               int N, int row0) {
  __shared__ float tile[32][33];
  const int k0 = blockIdx.x * 32, n0 = blockIdx.y * 32;
  const int tx = threadIdx.x & 31, ty = threadIdx.x >> 5;  // 32x8
#pragma unroll
  for (int i = 0; i < 32; i += 8)
    tile[ty + i][tx] = W[(long)(k0 + ty + i) * N + n0 + tx];
  __syncthreads();
#pragma unroll
  for (int i = 0; i < 32; i += 8)
    Wt[(long)(row0 + n0 + ty + i) * K + k0 + tx] = (bf16_t)tile[tx][ty + i];
}

// ---------------- per-head lambda ----------------
__global__ void lam_kernel(const float* __restrict__ lq1,
                           const float* __restrict__ lk1,
                           const float* __restrict__ lq2,
                           const float* __restrict__ lk2,
                           float* __restrict__ lam) {
  const int h = threadIdx.x;
  if (h < NH) {
    float d1 = 0.f, d2 = 0.f;
    for (int i = 0; i < 64; ++i) {
      d1 += lq1[h * 64 + i] * lk1[h * 64 + i];
      d2 += lq2[h * 64 + i] * lk2[h * 64 + i];
    }
    lam[h] = expf(d1) - expf(d2) + LAMBDA_INIT;
  }
}

// ---------------- GEMM (m97 structure): C[M][N] = A[M][K] @ Bt[N][K]^T -------
#define BM 128
#define BN 128
#define BK 32

template <typename OutT>
__global__ void __launch_bounds__(256) gemm_bt(const bf16_t* __restrict__ A,
                                               const bf16_t* __restrict__ Bt,
                                               OutT* __restrict__ C, int M,
                                               int N, int K) {
  __shared__ __align__(16) bf16_t As[BM * BK];
  __shared__ __align__(16) bf16_t Bs[BN * BK];
  const int tid = threadIdx.x;
  const int w = tid >> 6;
  const int lane = tid & 63;
  const int quad = lane >> 4, l16 = lane & 15;
  const int m0 = blockIdx.y * BM, n0 = blockIdx.x * BN;
  const int wm = (w >> 1) * 64, wn = (w & 1) * 64;
  const int srow = tid >> 2;       // 0..63
  const int scol = (tid & 3) * 8;  // 0,8,16,24

  const bf16_t* Ag0 = A + (long)(m0 + srow) * K + scol;
  const bf16_t* Ag1 = Ag0 + (long)64 * K;
  const bf16_t* Bg0 = Bt + (long)(n0 + srow) * K + scol;
  const bf16_t* Bg1 = Bg0 + (long)64 * K;
  bf16_t* lA0 = As + tid * 8;  // == srow*32 + scol
  bf16_t* lA1 = As + 2048 + tid * 8;
  bf16_t* lB0 = Bs + tid * 8;
  bf16_t* lB1 = Bs + 2048 + tid * 8;

  f32x4 acc[4][4] = {};

  for (int k0 = 0; k0 < K; k0 += BK) {
    GLDS(Ag0 + k0, lA0);
    GLDS(Ag1 + k0, lA1);
    GLDS(Bg0 + k0, lB0);
    GLDS(Bg1 + k0, lB1);
    __syncthreads();
    bf16x8 af[4], bfr[4];
#pragma unroll
    for (int t = 0; t < 4; ++t) {
      af[t] = *(const bf16x8*)(As + (wm + t * 16 + l16) * BK + quad * 8);
      bfr[t] = *(const bf16x8*)(Bs + (wn + t * 16 + l16) * BK + quad * 8);
    }
#pragma unroll
    for (int mt = 0; mt < 4; ++mt)
#pragma unroll
      for (int nt = 0; nt < 4; ++nt)
        acc[mt][nt] = __builtin_amdgcn_mfma_f32_16x16x32_bf16(
            af[mt], bfr[nt], acc[mt][nt], 0, 0, 0);
    __syncthreads();
  }

#pragma unroll
  for (int mt = 0; mt < 4; ++mt)
#pragma unroll
    for (int nt = 0; nt < 4; ++nt) {
      const int col = n0 + wn + nt * 16 + l16;
#pragma unroll
      for (int i = 0; i < 4; ++i) {
        const int row = m0 + wm + mt * 16 + quad * 4 + i;
        C[(long)row * N + col] = (OutT)acc[mt][nt][i];
      }
    }
}

// ---------------- transpose v slice of proj -> vt[(b,h)][d][t] ----------------
__global__ void __launch_bounds__(256) transpose_v(const bf16_t* __restrict__ proj,
                                                   bf16_t* __restrict__ vt) {
  __shared__ bf16_t tile[32][34];
  const int bh = blockIdx.z;
  const int b = bh >> 4, h = bh & 15;
  const int t0 = blockIdx.x * 32, d0 = blockIdx.y * 32;
  const int tx = threadIdx.x & 31, ty = threadIdx.x >> 5;
  const bf16_t* src = proj + (long)(b * T_SEQ) * NPROJ + 4096 + h * 128;
#pragma unroll
  for (int i = 0; i < 32; i += 8)
    tile[ty + i][tx] = src[(long)(t0 + ty + i) * NPROJ + d0 + tx];
  __syncthreads();
  bf16_t* dst = vt + ((long)(b * NH + h) * DV) * T_SEQ;
#pragma unroll
  for (int i = 0; i < 32; i += 8)
    dst[(long)(d0 + ty + i) * T_SEQ + t0 + tx] = tile[tx][ty + i];
}

// ---------------- attention: reg->LDS staged dual-softmax flash + subLN -----
// grid: (T/64, H, B), block 256 (4 waves; wave w owns q rows q0..q0+15).
// All 4 waves share one (b,h). Per 32-key tile, each thread stages 32 bf16:
// K1/K2 row (tid>>3, dims (tid&7)*8) and V dims (tid>>2, 64+tid>>2), keys
// (tid&3)*8. All LDS slots are base + tid*8 (identity: coalesced + conflict-
// free). Next tile is prefetched into registers during compute.
__global__ void __launch_bounds__(256) attn_kernel(const bf16_t* __restrict__ proj,
                                                   const bf16_t* __restrict__ vt,
                                                   const float* __restrict__ lamp,
                                                   bf16_t* __restrict__ yln) {
  const int qblk = (gridDim.x - 1) - blockIdx.x;  // heavy blocks first
  const int h = blockIdx.y;
  const int b = blockIdx.z;
  const int tid = threadIdx.x;
  const int w = tid >> 6, lane = tid & 63;
  const int quad = lane >> 4, l16 = lane & 15;
  const int q0 = qblk * 64 + w * 16;
  const long bT = (long)b * T_SEQ;

  __shared__ __align__(16) bf16_t Ks1[32 * 64];  // [key][dim]
  __shared__ __align__(16) bf16_t Ks2[32 * 64];  // [key][dim]
  __shared__ __align__(16) bf16_t Vs[DV * 32];   // [dim][key]
  __shared__ __align__(16) bf16_t pbuf[4][2][16 * 40];

  // ---- Q fragments (registers for whole kernel) ----
  const bf16_t* qrow = proj + (bT + q0 + l16) * (long)NPROJ + h * 64;
  bf16x8 aq1[2], aq2[2];
  aq1[0] = *(const bf16x8*)(qrow + quad * 8);
  aq1[1] = *(const bf16x8*)(qrow + 32 + quad * 8);
  aq2[0] = *(const bf16x8*)(qrow + 1024 + quad * 8);
  aq2[1] = *(const bf16x8*)(qrow + 1024 + 32 + quad * 8);

  f32x4 O1[8] = {}, O2[8] = {};
  float m1[4], l1[4], m2[4], l2[4];
#pragma unroll
  for (int i = 0; i < 4; ++i) {
    m1[i] = -3.0e38f;
    m2[i] = -3.0e38f;
    l1[i] = 0.f;
    l2[i] = 0.f;
  }

  // ---- staging source pointers ----
  const bf16_t* gK1 =
      proj + (bT + (tid >> 3)) * (long)NPROJ + h * 64 + 2048 + (tid & 7) * 8;
  const bf16_t* gK2 = gK1 + 1024;
  const bf16_t* vbase = vt + ((long)(b * NH + h) * DV) * T_SEQ;
  const bf16_t* gV0 = vbase + (long)(tid >> 2) * T_SEQ + (tid & 3) * 8;
  const bf16_t* gV1 = gV0 + (long)64 * T_SEQ;

  bf16_t* pb1 = &pbuf[w][0][0];
  bf16_t* pb2 = &pbuf[w][1][0];
  const float sc = 0.125f * LOG2E;  // 1/sqrt(64) folded with log2(e)

  const int kend_blk = qblk * 64 + 64;  // block-level exclusive key bound
  const int kend_w = q0 + 16;           // this wave's exclusive key bound

  // ---- prime the register pipeline with tile kt=0 ----
  bf16x8 rK1 = *(const bf16x8*)(gK1);
  bf16x8 rK2 = *(const bf16x8*)(gK2);
  bf16x8 rV0 = *(const bf16x8*)(gV0);
  bf16x8 rV1 = *(const bf16x8*)(gV1);

  for (int kt = 0; kt < kend_blk; kt += 32) {
    // ---- commit staged registers to LDS ----
    *(bf16x8*)(Ks1 + tid * 8) = rK1;
    *(bf16x8*)(Ks2 + tid * 8) = rK2;
    *(bf16x8*)(Vs + tid * 8) = rV0;
    *(bf16x8*)(Vs + 2048 + tid * 8) = rV1;
    __syncthreads();

    // ---- prefetch next tile into registers (overlaps compute) ----
    if (kt + 32 < kend_blk) {
      const long ko = (long)(kt + 32) * NPROJ;
      rK1 = *(const bf16x8*)(gK1 + ko);
      rK2 = *(const bf16x8*)(gK2 + ko);
      rV0 = *(const bf16x8*)(gV0 + kt + 32);
      rV1 = *(const bf16x8*)(gV1 + kt + 32);
    }

    if (kt < kend_w) {
      // ---- S = Q K^T, 16x32 tile as two 16x16 C-frags per stream ----
      f32x4 s1[2], s2[2];
#pragma unroll
      for (int c = 0; c < 2; ++c) {
        const bf16_t* kr1 = Ks1 + (c * 16 + l16) * 64;
        const bf16_t* kr2 = Ks2 + (c * 16 + l16) * 64;
        bf16x8 b10 = *(const bf16x8*)(kr1 + quad * 8);
        bf16x8 b11 = *(const bf16x8*)(kr1 + 32 + quad * 8);
        f32x4 z = {};
        z = __builtin_amdgcn_mfma_f32_16x16x32_bf16(aq1[0], b10, z, 0, 0, 0);
        z = __builtin_amdgcn_mfma_f32_16x16x32_bf16(aq1[1], b11, z, 0, 0, 0);
        s1[c] = z;
        bf16x8 b20 = *(const bf16x8*)(kr2 + quad * 8);
        bf16x8 b21 = *(const bf16x8*)(kr2 + 32 + quad * 8);
        f32x4 z2 = {};
        z2 = __builtin_amdgcn_mfma_f32_16x16x32_bf16(aq2[0], b20, z2, 0, 0, 0);
        z2 = __builtin_amdgcn_mfma_f32_16x16x32_bf16(aq2[1], b21, z2, 0, 0, 0);
        s2[c] = z2;
      }
      // ---- scale + causal mask (only diagonal tiles need the mask) ----
      const bool need_mask = (kt + 31 > q0);
      float t1[2][4], t2[2][4], mx1[4], mx2[4];
#pragma unroll
      for (int i = 0; i < 4; ++i) {
        mx1[i] = -3.0e38f;
        mx2[i] = -3.0e38f;
      }
#pragma unroll
      for (int c = 0; c < 2; ++c) {
        const int col = kt + c * 16 + l16;
#pragma unroll
        for (int i = 0; i < 4; ++i) {
          const int row = q0 + quad * 4 + i;
          float v1 = s1[c][i] * sc, v2 = s2[c][i] * sc;
          if (need_mask && col > row) {
            v1 = -1e30f;
            v2 = -1e30f;
          }
          t1[c][i] = v1;
          t2[c][i] = v2;
          mx1[i] = fmaxf(mx1[i], v1);
          mx2[i] = fmaxf(mx2[i], v2);
        }
      }
#pragma unroll
      for (int s = 1; s < 16; s <<= 1)
#pragma unroll
        for (int i = 0; i < 4; ++i) {
          mx1[i] = fmaxf(mx1[i], __shfl_xor(mx1[i], s));
          mx2[i] = fmaxf(mx2[i], __shfl_xor(mx2[i], s));
        }
      float al1[4], al2[4];
#pragma unroll
      for (int i = 0; i < 4; ++i) {
        float mn = fmaxf(m1[i], mx1[i]);
        al1[i] = exp2f(m1[i] - mn);
        m1[i] = mn;
        mn = fmaxf(m2[i], mx2[i]);
        al2[i] = exp2f(m2[i] - mn);
        m2[i] = mn;
      }
      // ---- P = exp2(t - m) -> LDS (C->A layout transform) ----
      float sum1[4] = {0, 0, 0, 0}, sum2[4] = {0, 0, 0, 0};
#pragma unroll
      for (int c = 0; c < 2; ++c)
#pragma unroll
        for (int i = 0; i < 4; ++i) {
          bf16_t p1 = (bf16_t)exp2f(t1[c][i] - m1[i]);
          bf16_t p2 = (bf16_t)exp2f(t2[c][i] - m2[i]);
          pb1[(quad * 4 + i) * 40 + c * 16 + l16] = p1;
          pb2[(quad * 4 + i) * 40 + c * 16 + l16] = p2;
          sum1[i] += (float)p1;
          sum2[i] += (float)p2;
        }
#pragma unroll
      for (int s = 1; s < 16; s <<= 1)
#pragma unroll
        for (int i = 0; i < 4; ++i) {
          sum1[i] += __shfl_xor(sum1[i], s);
          sum2[i] += __shfl_xor(sum2[i], s);
        }
#pragma unroll
      for (int i = 0; i < 4; ++i) {
        l1[i] = l1[i] * al1[i] + sum1[i];
        l2[i] = l2[i] * al2[i] + sum2[i];
      }
#pragma unroll
      for (int f = 0; f < 8; ++f)
#pragma unroll
        for (int i = 0; i < 4; ++i) {
          O1[f][i] *= al1[i];
          O2[f][i] *= al2[i];
        }
      __asm__ volatile("s_waitcnt lgkmcnt(0)" ::: "memory");
      bf16x8 ap1 = *(const bf16x8*)(pb1 + l16 * 40 + quad * 8);
      bf16x8 ap2 = *(const bf16x8*)(pb2 + l16 * 40 + quad * 8);
      // ---- PV: O += P @ V (V frags from LDS, shared between streams) ----
#pragma unroll
      for (int f = 0; f < 8; ++f) {
        bf16x8 bv = *(const bf16x8*)(Vs + (f * 16 + l16) * 32 + quad * 8);
        O1[f] = __builtin_amdgcn_mfma_f32_16x16x32_bf16(ap1, bv, O1[f], 0, 0, 0);
        O2[f] = __builtin_amdgcn_mfma_f32_16x16x32_bf16(ap2, bv, O2[f], 0, 0, 0);
      }
    }
    __syncthreads();
  }

  // ---- combine streams, subLN over 128 dims, scale, store bf16 ----
  const float lam = lamp[h];
  float inv1[4], inv2[4];
#pragma unroll
  for (int i = 0; i < 4; ++i) {
    inv1[i] = 1.0f / l1[i];
    inv2[i] = lam / l2[i];
  }
  float sm[4] = {0, 0, 0, 0}, sq[4] = {0, 0, 0, 0};
#pragma unroll
  for (int f = 0; f < 8; ++f)
#pragma unroll
    for (int i = 0; i < 4; ++i) {
      float y = O1[f][i] * inv1[i] - O2[f][i] * inv2[i];
      O1[f][i] = y;
      sm[i] += y;
      sq[i] += y * y;
    }
#pragma unroll
  for (int s = 1; s < 16; s <<= 1)
#pragma unroll
    for (int i = 0; i < 4; ++i) {
      sm[i] += __shfl_xor(sm[i], s);
      sq[i] += __shfl_xor(sq[i], s);
    }
  float mu[4], rs[4];
#pragma unroll
  for (int i = 0; i < 4; ++i) {
    mu[i] = sm[i] * (1.0f / 128.0f);
    float var = sq[i] * (1.0f / 128.0f) - mu[i] * mu[i];
    rs[i] = rsqrtf(var + 1e-5f) * ONE_MINUS_LI;
  }
#pragma unroll
  for (int i = 0; i < 4; ++i) {
    bf16_t* dst = yln + (bT + q0 + quad * 4 + i) * (long)2048 + h * 128 + l16;
#pragma unroll
    for (int f = 0; f < 8; ++f)
      dst[f * 16] = (bf16_t)((O1[f][i] - mu[i]) * rs[i]);
  }
}

// ---------------------------------------------------------------------------
extern "C" void kernel_launch(void* const* d_in, const int* in_sizes, int n_in,
                              void* d_out, int out_size, void* d_ws,
                              size_t ws_size, hipStream_t stream) {
  const float* x = (const float*)d_in[0];
  const float* Wq1 = (const float*)d_in[1];
  const float* Wq2 = (const float*)d_in[2];
  const float* Wk1 = (const float*)d_in[3];
  const float* Wk2 = (const float*)d_in[4];
  const float* Wv = (const float*)d_in[5];
  const float* Wc = (const float*)d_in[6];
  const float* lq1 = (const float*)d_in[7];
  const float* lk1 = (const float*)d_in[8];
  const float* lq2 = (const float*)d_in[9];
  const float* lk2 = (const float*)d_in[10];
  float* out = (float*)d_out;

  char* ws = (char*)d_ws;
  bf16_t* wcat = (bf16_t*)(ws + OFF_WCAT);
  bf16_t* xb = (bf16_t*)(ws + OFF_XB);
  bf16_t* wct = (bf16_t*)(ws + OFF_WCT);
  bf16_t* projb = (bf16_t*)(ws + OFF_PROJ);
  bf16_t* vtb = (bf16_t*)(ws + OFF_VT);
  bf16_t* ylnb = (bf16_t*)(ws + OFF_YLN);
  float* lamp = (float*)(ws + OFF_LAM);

  cast_x<<<4096, 256, 0, stream>>>(x, xb);
  tcast_w<<<dim3(32, 32), 256, 0, stream>>>(Wq1, wcat, 1024, 1024, 0);
  tcast_w<<<dim3(32, 32), 256, 0, stream>>>(Wq2, wcat, 1024, 1024, 1024);
  tcast_w<<<dim3(32, 32), 256, 0, stream>>>(Wk1, wcat, 1024, 1024, 2048);
  tcast_w<<<dim3(32, 32), 256, 0, stream>>>(Wk2, wcat, 1024, 1024, 3072);
  tcast_w<<<dim3(32, 64), 256, 0, stream>>>(Wv, wcat, 1024, 2048, 4096);
  tcast_w<<<dim3(64, 32), 256, 0, stream>>>(Wc, wct, 2048, 1024, 0);
  lam_kernel<<<1, 64, 0, stream>>>(lq1, lk1, lq2, lk2, lamp);

  // proj = xb @ wcat^T : M=4096 N=6144 K=1024
  gemm_bt<bf16_t><<<dim3(48, 32), 256, 0, stream>>>(xb, wcat, projb, 4096, 6144, 1024);
  transpose_v<<<dim3(32, 4, 64), 256, 0, stream>>>(projb, vtb);
  attn_kernel<<<dim3(16, 16, 4), 256, 0, stream>>>(projb, vtb, lamp, ylnb);
  // out = yln @ wc^T : M=4096 N=1024 K=2048
  gemm_bt<float><<<dim3(8, 32), 256, 0, stream>>>(ylnb, wct, out, 4096, 1024, 2048);
}

// Round 5
// 410.635 us; speedup vs baseline: 1.2308x; 1.1244x over previous
//
#include <hip/hip_runtime.h>

// ---------------------------------------------------------------------------
// DiffAttention forward, bf16 MFMA pipeline.  B=4 T=1024 C=1024 H=16 hs=64 dv=128.
//   1. cast x -> bf16; transpose-cast weights -> W^T[n][k] bf16
//   2. proj GEMM (m97-style global_load_lds): proj[4096][6144] = xb @ wcat^T
//   3. transpose v slice -> vt[(b,h)][dim][token]
//   4. attention: reg->LDS staged, ONLINE max-tracked dual softmax (R3-exact
//      numerics), DPP-row16 reductions (no LDS-pipe shuffles), fused subLN
//   5. out GEMM: out[4096][1024] fp32 = yln @ wc^T
// MFMA mappings (HW-verified): A[m=lane&15][k=quad*8+j]; B^T[n=lane&15][k=...]
// C/D: col=lane&15, row=quad*4+reg.
// R4 lesson: fixed-max softmax (p up to ~10 instead of <=1) degraded absmax
// 0.034 -> 0.125. Reverted to online max (R3-verified); perf attacked via
// DPP reductions + K LDS stride 72 (R3 stride-64 aliased 64 lanes onto 16
// banks: 9.2M SQ_LDS_BANK_CONFLICT).
// ---------------------------------------------------------------------------

#define T_SEQ 1024
#define NH 16
#define DV 128
#define NPROJ 6144
#define KSTR 72  // padded K LDS row stride (elements)

typedef __bf16 bf16_t;
typedef __bf16 bf16x8 __attribute__((ext_vector_type(8)));
typedef __bf16 bf16x4 __attribute__((ext_vector_type(4)));
typedef float f32x4 __attribute__((ext_vector_type(4)));

#define LAMBDA_INIT 0.35550906759096928f
#define ONE_MINUS_LI 0.6444909324090307f
#define LOG2E 1.4426950408889634f

// async global->LDS, 16B/lane (gemm only).
#define GLDS(g, l)                                                            \
  __builtin_amdgcn_global_load_lds(                                           \
      (const __attribute__((address_space(1))) void*)(g),                     \
      (__attribute__((address_space(3))) void*)(l), 16, 0, 0)

// ---- DPP 16-lane reductions (groups == DPP rows of 16) ----
template <int C>
__device__ __forceinline__ float dppf(float x) {
  return __builtin_bit_cast(
      float, __builtin_amdgcn_update_dpp(0, __builtin_bit_cast(int, x), C,
                                         0xF, 0xF, true));
}
__device__ __forceinline__ float row16_max(float x) {
  x = fmaxf(x, dppf<0xB1>(x));   // quad_perm [1,0,3,2]  (xor 1)
  x = fmaxf(x, dppf<0x4E>(x));   // quad_perm [2,3,0,1]  (xor 2)
  x = fmaxf(x, dppf<0x124>(x));  // row_ror:4
  x = fmaxf(x, dppf<0x128>(x));  // row_ror:8
  return x;
}
__device__ __forceinline__ float row16_sum(float x) {
  x += dppf<0xB1>(x);
  x += dppf<0x4E>(x);
  x += dppf<0x124>(x);
  x += dppf<0x128>(x);
  return x;
}

// ---------------- workspace layout (bytes) ----------------
static const size_t OFF_WCAT = 0;                                  // 6144x1024 bf16
static const size_t OFF_XB = OFF_WCAT + (size_t)6144 * 1024 * 2;   // 4096x1024 bf16
static const size_t OFF_WCT = OFF_XB + (size_t)4096 * 1024 * 2;    // 1024x2048 bf16
static const size_t OFF_PROJ = OFF_WCT + (size_t)2048 * 1024 * 2;  // 4096x6144 bf16
static const size_t OFF_VT = OFF_PROJ + (size_t)4096 * 6144 * 2;   // 64*128*1024 bf16
static const size_t OFF_YLN = OFF_VT + (size_t)64 * 128 * 1024 * 2;// 4096x2048 bf16
static const size_t OFF_LAM = OFF_YLN + (size_t)4096 * 2048 * 2;   // 16 f32

// ---------------- elementwise cast x -> bf16 ----------------
__global__ void __launch_bounds__(256) cast_x(const float* __restrict__ x,
                                              bf16_t* __restrict__ o) {
  const int i = (blockIdx.x * 256 + threadIdx.x) * 4;
  float4 v = *(const float4*)(x + i);
  bf16x4 r = {(bf16_t)v.x, (bf16_t)v.y, (bf16_t)v.z, (bf16_t)v.w};
  *(bf16x4*)(o + i) = r;
}

// ---------------- transpose-cast weight W[K][N] fp32 -> Wt[row0+n][k] bf16 ----
__device__ __forceinline__ void tcast_body(const float* __restrict__ W,
                                           bf16_t* __restrict__ Wt, int K,
                                           int N, int row0) {
  __shared__ float tile[32][33];
  const int k0 = blockIdx.x * 32, n0 = blockIdx.y * 32;
  const int tx = threadIdx.x & 31, ty = threadIdx.x >> 5;  // 32x8
#pragma unroll
  for (int i = 0; i < 32; i += 8)
    tile[ty + i][tx] = W[(long)(k0 + ty + i) * N + n0 + tx];
  __syncthreads();
#pragma unroll
  for (int i = 0; i < 32; i += 8)
    Wt[(long)(row0 + n0 + ty + i) * K + k0 + tx] = (bf16_t)tile[tx][ty + i];
}

__global__ void __launch_bounds__(256) tcast_w(const float* __restrict__ W,
                                               bf16_t* __restrict__ Wt, int K,
                                               int N, int row0) {
  tcast_body(W, Wt, K, N, row0);
}

// fused: the four 1024x1024 q/k weights in one launch (z selects)
__global__ void __launch_bounds__(256) tcast_w4(const float* __restrict__ W0,
                                                const float* __restrict__ W1,
                                                const float* __restrict__ W2,
                                                const float* __restrict__ W3,
                                                bf16_t* __restrict__ Wt) {
  const float* Ws[4] = {W0, W1, W2, W3};
  tcast_body(Ws[blockIdx.z], Wt, 1024, 1024, blockIdx.z * 1024);
}

// ---------------- per-head lambda ----------------
__global__ void lam_kernel(const float* __restrict__ lq1,
                           const float* __restrict__ lk1,
                           const float* __restrict__ lq2,
                           const float* __restrict__ lk2,
                           float* __restrict__ lam) {
  const int h = threadIdx.x;
  if (h < NH) {
    float d1 = 0.f, d2 = 0.f;
    for (int i = 0; i < 64; ++i) {
      d1 += lq1[h * 64 + i] * lk1[h * 64 + i];
      d2 += lq2[h * 64 + i] * lk2[h * 64 + i];
    }
    lam[h] = expf(d1) - expf(d2) + LAMBDA_INIT;
  }
}

// ---------------- GEMM (m97 structure): C[M][N] = A[M][K] @ Bt[N][K]^T -------
#define BM 128
#define BN 128
#define BK 32

template <typename OutT>
__global__ void __launch_bounds__(256) gemm_bt(const bf16_t* __restrict__ A,
                                               const bf16_t* __restrict__ Bt,
                                               OutT* __restrict__ C, int M,
                                               int N, int K) {
  __shared__ __align__(16) bf16_t As[BM * BK];
  __shared__ __align__(16) bf16_t Bs[BN * BK];
  const int tid = threadIdx.x;
  const int w = tid >> 6;
  const int lane = tid & 63;
  const int quad = lane >> 4, l16 = lane & 15;
  const int m0 = blockIdx.y * BM, n0 = blockIdx.x * BN;
  const int wm = (w >> 1) * 64, wn = (w & 1) * 64;
  const int srow = tid >> 2;       // 0..63
  const int scol = (tid & 3) * 8;  // 0,8,16,24

  const bf16_t* Ag0 = A + (long)(m0 + srow) * K + scol;
  const bf16_t* Ag1 = Ag0 + (long)64 * K;
  const bf16_t* Bg0 = Bt + (long)(n0 + srow) * K + scol;
  const bf16_t* Bg1 = Bg0 + (long)64 * K;
  bf16_t* lA0 = As + tid * 8;  // == srow*32 + scol
  bf16_t* lA1 = As + 2048 + tid * 8;
  bf16_t* lB0 = Bs + tid * 8;
  bf16_t* lB1 = Bs + 2048 + tid * 8;

  f32x4 acc[4][4] = {};

  for (int k0 = 0; k0 < K; k0 += BK) {
    GLDS(Ag0 + k0, lA0);
    GLDS(Ag1 + k0, lA1);
    GLDS(Bg0 + k0, lB0);
    GLDS(Bg1 + k0, lB1);
    __syncthreads();
    bf16x8 af[4], bfr[4];
#pragma unroll
    for (int t = 0; t < 4; ++t) {
      af[t] = *(const bf16x8*)(As + (wm + t * 16 + l16) * BK + quad * 8);
      bfr[t] = *(const bf16x8*)(Bs + (wn + t * 16 + l16) * BK + quad * 8);
    }
#pragma unroll
    for (int mt = 0; mt < 4; ++mt)
#pragma unroll
      for (int nt = 0; nt < 4; ++nt)
        acc[mt][nt] = __builtin_amdgcn_mfma_f32_16x16x32_bf16(
            af[mt], bfr[nt], acc[mt][nt], 0, 0, 0);
    __syncthreads();
  }

#pragma unroll
  for (int mt = 0; mt < 4; ++mt)
#pragma unroll
    for (int nt = 0; nt < 4; ++nt) {
      const int col = n0 + wn + nt * 16 + l16;
#pragma unroll
      for (int i = 0; i < 4; ++i) {
        const int row = m0 + wm + mt * 16 + quad * 4 + i;
        C[(long)row * N + col] = (OutT)acc[mt][nt][i];
      }
    }
}

// ---------------- transpose v slice of proj -> vt[(b,h)][d][t] ----------------
__global__ void __launch_bounds__(256) transpose_v(const bf16_t* __restrict__ proj,
                                                   bf16_t* __restrict__ vt) {
  __shared__ bf16_t tile[32][34];
  const int bh = blockIdx.z;
  const int b = bh >> 4, h = bh & 15;
  const int t0 = blockIdx.x * 32, d0 = blockIdx.y * 32;
  const int tx = threadIdx.x & 31, ty = threadIdx.x >> 5;
  const bf16_t* src = proj + (long)(b * T_SEQ) * NPROJ + 4096 + h * 128;
#pragma unroll
  for (int i = 0; i < 32; i += 8)
    tile[ty + i][tx] = src[(long)(t0 + ty + i) * NPROJ + d0 + tx];
  __syncthreads();
  bf16_t* dst = vt + ((long)(b * NH + h) * DV) * T_SEQ;
#pragma unroll
  for (int i = 0; i < 32; i += 8)
    dst[(long)(d0 + ty + i) * T_SEQ + t0 + tx] = tile[tx][ty + i];
}

// ---------------- attention: reg->LDS staged dual-softmax flash + subLN -----
// grid: (T/64, H, B), block 256 (4 waves; wave w owns q rows q0..q0+15).
// Online max-tracked softmax (R3-exact numerics); all 16-lane row reductions
// via DPP (VALU-speed) instead of __shfl_xor (LDS-pipe latency).
__global__ void __launch_bounds__(256) attn_kernel(const bf16_t* __restrict__ proj,
                                                   const bf16_t* __restrict__ vt,
                                                   const float* __restrict__ lamp,
                                                   bf16_t* __restrict__ yln) {
  const int qblk = (gridDim.x - 1) - blockIdx.x;  // heavy blocks first
  const int h = blockIdx.y;
  const int b = blockIdx.z;
  const int tid = threadIdx.x;
  const int w = tid >> 6, lane = tid & 63;
  const int quad = lane >> 4, l16 = lane & 15;
  const int q0 = qblk * 64 + w * 16;
  const long bT = (long)b * T_SEQ;

  __shared__ __align__(16) bf16_t Ks1[32 * KSTR];  // [key][dim], padded
  __shared__ __align__(16) bf16_t Ks2[32 * KSTR];
  __shared__ __align__(16) bf16_t Vs[DV * 32];     // [dim][key]
  __shared__ __align__(16) bf16_t pbuf[4][2][16 * 40];

  // ---- Q fragments (registers for whole kernel) ----
  const bf16_t* qrow = proj + (bT + q0 + l16) * (long)NPROJ + h * 64;
  bf16x8 aq1[2], aq2[2];
  aq1[0] = *(const bf16x8*)(qrow + quad * 8);
  aq1[1] = *(const bf16x8*)(qrow + 32 + quad * 8);
  aq2[0] = *(const bf16x8*)(qrow + 1024 + quad * 8);
  aq2[1] = *(const bf16x8*)(qrow + 1024 + 32 + quad * 8);

  f32x4 O1[8] = {}, O2[8] = {};
  float m1[4], l1[4], m2[4], l2[4];
#pragma unroll
  for (int i = 0; i < 4; ++i) {
    m1[i] = -3.0e38f;
    m2[i] = -3.0e38f;
    l1[i] = 0.f;
    l2[i] = 0.f;
  }

  // ---- staging source pointers ----
  const bf16_t* gK1 =
      proj + (bT + (tid >> 3)) * (long)NPROJ + h * 64 + 2048 + (tid & 7) * 8;
  const bf16_t* gK2 = gK1 + 1024;
  const bf16_t* vbase = vt + ((long)(b * NH + h) * DV) * T_SEQ;
  const bf16_t* gV0 = vbase + (long)(tid >> 2) * T_SEQ + (tid & 3) * 8;
  const bf16_t* gV1 = gV0 + (long)64 * T_SEQ;
  const int kw = (tid >> 3) * KSTR + (tid & 7) * 8;  // padded K write slot

  bf16_t* pb1 = &pbuf[w][0][0];
  bf16_t* pb2 = &pbuf[w][1][0];
  const float sc = 0.125f * LOG2E;  // 1/sqrt(64) folded with log2(e)

  const int kend_blk = qblk * 64 + 64;  // block-level exclusive key bound
  const int kend_w = q0 + 16;           // this wave's exclusive key bound

  // ---- prime the register pipeline with tile kt=0 ----
  bf16x8 rK1 = *(const bf16x8*)(gK1);
  bf16x8 rK2 = *(const bf16x8*)(gK2);
  bf16x8 rV0 = *(const bf16x8*)(gV0);
  bf16x8 rV1 = *(const bf16x8*)(gV1);

  for (int kt = 0; kt < kend_blk; kt += 32) {
    // ---- commit staged registers to LDS ----
    *(bf16x8*)(Ks1 + kw) = rK1;
    *(bf16x8*)(Ks2 + kw) = rK2;
    *(bf16x8*)(Vs + tid * 8) = rV0;
    *(bf16x8*)(Vs + 2048 + tid * 8) = rV1;
    __syncthreads();

    // ---- prefetch next tile into registers (overlaps compute) ----
    if (kt + 32 < kend_blk) {
      const long ko = (long)(kt + 32) * NPROJ;
      rK1 = *(const bf16x8*)(gK1 + ko);
      rK2 = *(const bf16x8*)(gK2 + ko);
      rV0 = *(const bf16x8*)(gV0 + kt + 32);
      rV1 = *(const bf16x8*)(gV1 + kt + 32);
    }

    if (kt < kend_w) {
      // ---- S = Q K^T, 16x32 tile as two 16x16 C-frags per stream ----
      f32x4 s1[2], s2[2];
#pragma unroll
      for (int c = 0; c < 2; ++c) {
        const bf16_t* kr1 = Ks1 + (c * 16 + l16) * KSTR;
        const bf16_t* kr2 = Ks2 + (c * 16 + l16) * KSTR;
        bf16x8 b10 = *(const bf16x8*)(kr1 + quad * 8);
        bf16x8 b11 = *(const bf16x8*)(kr1 + 32 + quad * 8);
        f32x4 z = {};
        z = __builtin_amdgcn_mfma_f32_16x16x32_bf16(aq1[0], b10, z, 0, 0, 0);
        z = __builtin_amdgcn_mfma_f32_16x16x32_bf16(aq1[1], b11, z, 0, 0, 0);
        s1[c] = z;
        bf16x8 b20 = *(const bf16x8*)(kr2 + quad * 8);
        bf16x8 b21 = *(const bf16x8*)(kr2 + 32 + quad * 8);
        f32x4 z2 = {};
        z2 = __builtin_amdgcn_mfma_f32_16x16x32_bf16(aq2[0], b20, z2, 0, 0, 0);
        z2 = __builtin_amdgcn_mfma_f32_16x16x32_bf16(aq2[1], b21, z2, 0, 0, 0);
        s2[c] = z2;
      }
      // ---- scale + causal mask (only diagonal tiles need the mask) ----
      const bool need_mask = (kt + 31 > q0);
      float t1[2][4], t2[2][4], mx1[4], mx2[4];
#pragma unroll
      for (int i = 0; i < 4; ++i) {
        mx1[i] = -3.0e38f;
        mx2[i] = -3.0e38f;
      }
#pragma unroll
      for (int c = 0; c < 2; ++c) {
        const int col = kt + c * 16 + l16;
#pragma unroll
        for (int i = 0; i < 4; ++i) {
          const int row = q0 + quad * 4 + i;
          float v1 = s1[c][i] * sc, v2 = s2[c][i] * sc;
          if (need_mask && col > row) {
            v1 = -1e30f;
            v2 = -1e30f;
          }
          t1[c][i] = v1;
          t2[c][i] = v2;
          mx1[i] = fmaxf(mx1[i], v1);
          mx2[i] = fmaxf(mx2[i], v2);
        }
      }
      // row max across 16 lanes (DPP)
#pragma unroll
      for (int i = 0; i < 4; ++i) {
        mx1[i] = row16_max(mx1[i]);
        mx2[i] = row16_max(mx2[i]);
      }
      float al1[4], al2[4];
#pragma unroll
      for (int i = 0; i < 4; ++i) {
        float mn = fmaxf(m1[i], mx1[i]);
        al1[i] = exp2f(m1[i] - mn);
        m1[i] = mn;
        mn = fmaxf(m2[i], mx2[i]);
        al2[i] = exp2f(m2[i] - mn);
        m2[i] = mn;
      }
      // ---- P = exp2(t - m) -> LDS (C->A layout transform) ----
      float sum1[4] = {0, 0, 0, 0}, sum2[4] = {0, 0, 0, 0};
#pragma unroll
      for (int c = 0; c < 2; ++c)
#pragma unroll
        for (int i = 0; i < 4; ++i) {
          bf16_t p1 = (bf16_t)exp2f(t1[c][i] - m1[i]);
          bf16_t p2 = (bf16_t)exp2f(t2[c][i] - m2[i]);
          pb1[(quad * 4 + i) * 40 + c * 16 + l16] = p1;
          pb2[(quad * 4 + i) * 40 + c * 16 + l16] = p2;
          sum1[i] += (float)p1;
          sum2[i] += (float)p2;
        }
      // row sum across 16 lanes (DPP)
#pragma unroll
      for (int i = 0; i < 4; ++i) {
        sum1[i] = row16_sum(sum1[i]);
        sum2[i] = row16_sum(sum2[i]);
      }
#pragma unroll
      for (int i = 0; i < 4; ++i) {
        l1[i] = l1[i] * al1[i] + sum1[i];
        l2[i] = l2[i] * al2[i] + sum2[i];
      }
#pragma unroll
      for (int f = 0; f < 8; ++f)
#pragma unroll
        for (int i = 0; i < 4; ++i) {
          O1[f][i] *= al1[i];
          O2[f][i] *= al2[i];
        }
      __asm__ volatile("s_waitcnt lgkmcnt(0)" ::: "memory");
      bf16x8 ap1 = *(const bf16x8*)(pb1 + l16 * 40 + quad * 8);
      bf16x8 ap2 = *(const bf16x8*)(pb2 + l16 * 40 + quad * 8);
      // ---- PV: O += P @ V (V frags from LDS, shared between streams) ----
#pragma unroll
      for (int f = 0; f < 8; ++f) {
        bf16x8 bv = *(const bf16x8*)(Vs + (f * 16 + l16) * 32 + quad * 8);
        O1[f] = __builtin_amdgcn_mfma_f32_16x16x32_bf16(ap1, bv, O1[f], 0, 0, 0);
        O2[f] = __builtin_amdgcn_mfma_f32_16x16x32_bf16(ap2, bv, O2[f], 0, 0, 0);
      }
    }
    __syncthreads();
  }

  // ---- combine streams, subLN over 128 dims, scale, store bf16 ----
  const float lam = lamp[h];
  float inv1[4], inv2[4];
#pragma unroll
  for (int i = 0; i < 4; ++i) {
    inv1[i] = 1.0f / l1[i];
    inv2[i] = lam / l2[i];
  }
  float sm[4], sq[4];
#pragma unroll
  for (int i = 0; i < 4; ++i) {
    sm[i] = 0.f;
    sq[i] = 0.f;
  }
#pragma unroll
  for (int f = 0; f < 8; ++f)
#pragma unroll
    for (int i = 0; i < 4; ++i) {
      float y = O1[f][i] * inv1[i] - O2[f][i] * inv2[i];
      O1[f][i] = y;
      sm[i] += y;
      sq[i] += y * y;
    }
#pragma unroll
  for (int i = 0; i < 4; ++i) {
    sm[i] = row16_sum(sm[i]);
    sq[i] = row16_sum(sq[i]);
  }
  float mu[4], rs[4];
#pragma unroll
  for (int i = 0; i < 4; ++i) {
    mu[i] = sm[i] * (1.0f / 128.0f);
    float var = sq[i] * (1.0f / 128.0f) - mu[i] * mu[i];
    rs[i] = rsqrtf(var + 1e-5f) * ONE_MINUS_LI;
  }
#pragma unroll
  for (int i = 0; i < 4; ++i) {
    bf16_t* dst = yln + (bT + q0 + quad * 4 + i) * (long)2048 + h * 128 + l16;
#pragma unroll
    for (int f = 0; f < 8; ++f)
      dst[f * 16] = (bf16_t)((O1[f][i] - mu[i]) * rs[i]);
  }
}

// ---------------------------------------------------------------------------
extern "C" void kernel_launch(void* const* d_in, const int* in_sizes, int n_in,
                              void* d_out, int out_size, void* d_ws,
                              size_t ws_size, hipStream_t stream) {
  const float* x = (const float*)d_in[0];
  const float* Wq1 = (const float*)d_in[1];
  const float* Wq2 = (const float*)d_in[2];
  const float* Wk1 = (const float*)d_in[3];
  const float* Wk2 = (const float*)d_in[4];
  const float* Wv = (const float*)d_in[5];
  const float* Wc = (const float*)d_in[6];
  const float* lq1 = (const float*)d_in[7];
  const float* lk1 = (const float*)d_in[8];
  const float* lq2 = (const float*)d_in[9];
  const float* lk2 = (const float*)d_in[10];
  float* out = (float*)d_out;

  char* ws = (char*)d_ws;
  bf16_t* wcat = (bf16_t*)(ws + OFF_WCAT);
  bf16_t* xb = (bf16_t*)(ws + OFF_XB);
  bf16_t* wct = (bf16_t*)(ws + OFF_WCT);
  bf16_t* projb = (bf16_t*)(ws + OFF_PROJ);
  bf16_t* vtb = (bf16_t*)(ws + OFF_VT);
  bf16_t* ylnb = (bf16_t*)(ws + OFF_YLN);
  float* lamp = (float*)(ws + OFF_LAM);

  cast_x<<<4096, 256, 0, stream>>>(x, xb);
  tcast_w4<<<dim3(32, 32, 4), 256, 0, stream>>>(Wq1, Wq2, Wk1, Wk2, wcat);
  tcast_w<<<dim3(32, 64), 256, 0, stream>>>(Wv, wcat, 1024, 2048, 4096);
  tcast_w<<<dim3(64, 32), 256, 0, stream>>>(Wc, wct, 2048, 1024, 0);
  lam_kernel<<<1, 64, 0, stream>>>(lq1, lk1, lq2, lk2, lamp);

  // proj = xb @ wcat^T : M=4096 N=6144 K=1024
  gemm_bt<bf16_t><<<dim3(48, 32), 256, 0, stream>>>(xb, wcat, projb, 4096, 6144, 1024);
  transpose_v<<<dim3(32, 4, 64), 256, 0, stream>>>(projb, vtb);
  attn_kernel<<<dim3(16, 16, 4), 256, 0, stream>>>(projb, vtb, lamp, ylnb);
  // out = yln @ wc^T : M=4096 N=1024 K=2048
  gemm_bt<float><<<dim3(8, 32), 256, 0, stream>>>(ylnb, wct, out, 4096, 1024, 2048);
}

// Round 6
// 368.267 us; speedup vs baseline: 1.3724x; 1.1150x over previous
//
#include <hip/hip_runtime.h>

// ---------------------------------------------------------------------------
// DiffAttention forward, bf16 MFMA pipeline.  B=4 T=1024 C=1024 H=16 hs=64 dv=128.
//   1. cast x -> bf16; transpose-cast weights -> W^T[n][k] bf16
//   2. proj GEMM (m97-style global_load_lds): proj[4096][6144] = xb @ wcat^T
//   3. transpose v slice -> vt[(b,h)][dim][token]
//   4. attention: qblk-PAIRED blocks (j with 15-j, sequential phases ->
//      uniform 34 staging iters/block; old grid stacked same-qblk blocks on
//      one CU: worst CU 128 iters), reg->LDS staged, online dual softmax,
//      DPP row16 reductions, XOR-swizzled P buffer, fused subLN
//   5. out GEMM: out[4096][1024] fp32 = yln @ wc^T
// MFMA mappings (HW-verified): A[m=lane&15][k=quad*8+j]; B^T[n=lane&15][k=...]
// C/D: col=lane&15, row=quad*4+reg.
// ---------------------------------------------------------------------------

#define T_SEQ 1024
#define NH 16
#define DV 128
#define NPROJ 6144
#define KSTR 72  // padded K LDS row stride (elements)

typedef __bf16 bf16_t;
typedef __bf16 bf16x8 __attribute__((ext_vector_type(8)));
typedef __bf16 bf16x4 __attribute__((ext_vector_type(4)));
typedef float f32x4 __attribute__((ext_vector_type(4)));

#define LAMBDA_INIT 0.35550906759096928f
#define ONE_MINUS_LI 0.6444909324090307f
#define LOG2E 1.4426950408889634f

// async global->LDS, 16B/lane (gemm only).
#define GLDS(g, l)                                                            \
  __builtin_amdgcn_global_load_lds(                                           \
      (const __attribute__((address_space(1))) void*)(g),                     \
      (__attribute__((address_space(3))) void*)(l), 16, 0, 0)

// ---- DPP 16-lane reductions (groups == DPP rows of 16) ----
template <int C>
__device__ __forceinline__ float dppf(float x) {
  return __builtin_bit_cast(
      float, __builtin_amdgcn_update_dpp(0, __builtin_bit_cast(int, x), C,
                                         0xF, 0xF, true));
}
__device__ __forceinline__ float row16_max(float x) {
  x = fmaxf(x, dppf<0xB1>(x));   // quad_perm xor1
  x = fmaxf(x, dppf<0x4E>(x));   // quad_perm xor2
  x = fmaxf(x, dppf<0x124>(x));  // row_ror:4
  x = fmaxf(x, dppf<0x128>(x));  // row_ror:8
  return x;
}
__device__ __forceinline__ float row16_sum(float x) {
  x += dppf<0xB1>(x);
  x += dppf<0x4E>(x);
  x += dppf<0x124>(x);
  x += dppf<0x128>(x);
  return x;
}

// ---------------- workspace layout (bytes) ----------------
static const size_t OFF_WCAT = 0;                                  // 6144x1024 bf16
static const size_t OFF_XB = OFF_WCAT + (size_t)6144 * 1024 * 2;   // 4096x1024 bf16
static const size_t OFF_WCT = OFF_XB + (size_t)4096 * 1024 * 2;    // 1024x2048 bf16
static const size_t OFF_PROJ = OFF_WCT + (size_t)2048 * 1024 * 2;  // 4096x6144 bf16
static const size_t OFF_VT = OFF_PROJ + (size_t)4096 * 6144 * 2;   // 64*128*1024 bf16
static const size_t OFF_YLN = OFF_VT + (size_t)64 * 128 * 1024 * 2;// 4096x2048 bf16
static const size_t OFF_LAM = OFF_YLN + (size_t)4096 * 2048 * 2;   // 16 f32

// ---------------- elementwise cast x -> bf16 ----------------
__global__ void __launch_bounds__(256) cast_x(const float* __restrict__ x,
                                              bf16_t* __restrict__ o) {
  const int i = (blockIdx.x * 256 + threadIdx.x) * 4;
  float4 v = *(const float4*)(x + i);
  bf16x4 r = {(bf16_t)v.x, (bf16_t)v.y, (bf16_t)v.z, (bf16_t)v.w};
  *(bf16x4*)(o + i) = r;
}

// ---------------- transpose-cast weight W[K][N] fp32 -> Wt[row0+n][k] bf16 ----
__device__ __forceinline__ void tcast_body(const float* __restrict__ W,
                                           bf16_t* __restrict__ Wt, int K,
                                           int N, int row0) {
  __shared__ float tile[32][33];
  const int k0 = blockIdx.x * 32, n0 = blockIdx.y * 32;
  const int tx = threadIdx.x & 31, ty = threadIdx.x >> 5;  // 32x8
#pragma unroll
  for (int i = 0; i < 32; i += 8)
    tile[ty + i][tx] = W[(long)(k0 + ty + i) * N + n0 + tx];
  __syncthreads();
#pragma unroll
  for (int i = 0; i < 32; i += 8)
    Wt[(long)(row0 + n0 + ty + i) * K + k0 + tx] = (bf16_t)tile[tx][ty + i];
}

__global__ void __launch_bounds__(256) tcast_w(const float* __restrict__ W,
                                               bf16_t* __restrict__ Wt, int K,
                                               int N, int row0) {
  tcast_body(W, Wt, K, N, row0);
}

// fused: the four 1024x1024 q/k weights in one launch (z selects)
__global__ void __launch_bounds__(256) tcast_w4(const float* __restrict__ W0,
                                                const float* __restrict__ W1,
                                                const float* __restrict__ W2,
                                                const float* __restrict__ W3,
                                                bf16_t* __restrict__ Wt) {
  const float* Ws[4] = {W0, W1, W2, W3};
  tcast_body(Ws[blockIdx.z], Wt, 1024, 1024, blockIdx.z * 1024);
}

// ---------------- per-head lambda ----------------
__global__ void lam_kernel(const float* __restrict__ lq1,
                           const float* __restrict__ lk1,
                           const float* __restrict__ lq2,
                           const float* __restrict__ lk2,
                           float* __restrict__ lam) {
  const int h = threadIdx.x;
  if (h < NH) {
    float d1 = 0.f, d2 = 0.f;
    for (int i = 0; i < 64; ++i) {
      d1 += lq1[h * 64 + i] * lk1[h * 64 + i];
      d2 += lq2[h * 64 + i] * lk2[h * 64 + i];
    }
    lam[h] = expf(d1) - expf(d2) + LAMBDA_INIT;
  }
}

// ---------------- GEMM (m97 structure): C[M][N] = A[M][K] @ Bt[N][K]^T -------
#define BM 128
#define BN 128
#define BK 32

template <typename OutT>
__global__ void __launch_bounds__(256) gemm_bt(const bf16_t* __restrict__ A,
                                               const bf16_t* __restrict__ Bt,
                                               OutT* __restrict__ C, int M,
                                               int N, int K) {
  __shared__ __align__(16) bf16_t As[BM * BK];
  __shared__ __align__(16) bf16_t Bs[BN * BK];
  const int tid = threadIdx.x;
  const int w = tid >> 6;
  const int lane = tid & 63;
  const int quad = lane >> 4, l16 = lane & 15;
  const int m0 = blockIdx.y * BM, n0 = blockIdx.x * BN;
  const int wm = (w >> 1) * 64, wn = (w & 1) * 64;
  const int srow = tid >> 2;       // 0..63
  const int scol = (tid & 3) * 8;  // 0,8,16,24

  const bf16_t* Ag0 = A + (long)(m0 + srow) * K + scol;
  const bf16_t* Ag1 = Ag0 + (long)64 * K;
  const bf16_t* Bg0 = Bt + (long)(n0 + srow) * K + scol;
  const bf16_t* Bg1 = Bg0 + (long)64 * K;
  bf16_t* lA0 = As + tid * 8;  // == srow*32 + scol
  bf16_t* lA1 = As + 2048 + tid * 8;
  bf16_t* lB0 = Bs + tid * 8;
  bf16_t* lB1 = Bs + 2048 + tid * 8;

  f32x4 acc[4][4] = {};

  for (int k0 = 0; k0 < K; k0 += BK) {
    GLDS(Ag0 + k0, lA0);
    GLDS(Ag1 + k0, lA1);
    GLDS(Bg0 + k0, lB0);
    GLDS(Bg1 + k0, lB1);
    __syncthreads();
    bf16x8 af[4], bfr[4];
#pragma unroll
    for (int t = 0; t < 4; ++t) {
      af[t] = *(const bf16x8*)(As + (wm + t * 16 + l16) * BK + quad * 8);
      bfr[t] = *(const bf16x8*)(Bs + (wn + t * 16 + l16) * BK + quad * 8);
    }
#pragma unroll
    for (int mt = 0; mt < 4; ++mt)
#pragma unroll
      for (int nt = 0; nt < 4; ++nt)
        acc[mt][nt] = __builtin_amdgcn_mfma_f32_16x16x32_bf16(
            af[mt], bfr[nt], acc[mt][nt], 0, 0, 0);
    __syncthreads();
  }

#pragma unroll
  for (int mt = 0; mt < 4; ++mt)
#pragma unroll
    for (int nt = 0; nt < 4; ++nt) {
      const int col = n0 + wn + nt * 16 + l16;
#pragma unroll
      for (int i = 0; i < 4; ++i) {
        const int row = m0 + wm + mt * 16 + quad * 4 + i;
        C[(long)row * N + col] = (OutT)acc[mt][nt][i];
      }
    }
}

// ---------------- transpose v slice of proj -> vt[(b,h)][d][t] ----------------
__global__ void __launch_bounds__(256) transpose_v(const bf16_t* __restrict__ proj,
                                                   bf16_t* __restrict__ vt) {
  __shared__ bf16_t tile[32][34];
  const int bh = blockIdx.z;
  const int b = bh >> 4, h = bh & 15;
  const int t0 = blockIdx.x * 32, d0 = blockIdx.y * 32;
  const int tx = threadIdx.x & 31, ty = threadIdx.x >> 5;
  const bf16_t* src = proj + (long)(b * T_SEQ) * NPROJ + 4096 + h * 128;
#pragma unroll
  for (int i = 0; i < 32; i += 8)
    tile[ty + i][tx] = src[(long)(t0 + ty + i) * NPROJ + d0 + tx];
  __syncthreads();
  bf16_t* dst = vt + ((long)(b * NH + h) * DV) * T_SEQ;
#pragma unroll
  for (int i = 0; i < 32; i += 8)
    dst[(long)(d0 + ty + i) * T_SEQ + t0 + tx] = tile[tx][ty + i];
}

// ---------------- attention: paired-qblk dual-softmax flash + subLN ---------
// grid: (8, H, B), block 256 (4 waves). Block p processes qblk 15-p then
// qblk p sequentially -> every block runs exactly 34 staging iterations
// (uniform makespan; the dispatcher stacks same-x blocks on one CU).
// P buffer: row stride 40 elem, 8-elem groups XOR-swizzled by (row>>2) so
// the scalar C-layout writes hit 32 distinct words (was 4-way conflicts).
__global__ void __launch_bounds__(256) attn_kernel(const bf16_t* __restrict__ proj,
                                                   const bf16_t* __restrict__ vt,
                                                   const float* __restrict__ lamp,
                                                   bf16_t* __restrict__ yln) {
  const int p = blockIdx.x;  // 0..7
  const int h = blockIdx.y;
  const int b = blockIdx.z;
  const int tid = threadIdx.x;
  const int w = tid >> 6, lane = tid & 63;
  const int quad = lane >> 4, l16 = lane & 15;
  const long bT = (long)b * T_SEQ;

  __shared__ __align__(16) bf16_t Ks1[32 * KSTR];  // [key][dim], padded
  __shared__ __align__(16) bf16_t Ks2[32 * KSTR];
  __shared__ __align__(16) bf16_t Vs[DV * 32];     // [dim][key]
  __shared__ __align__(16) bf16_t pbuf[4][2][16 * 40];

  // ---- staging source pointers (qblk-independent) ----
  const bf16_t* gK1 =
      proj + (bT + (tid >> 3)) * (long)NPROJ + h * 64 + 2048 + (tid & 7) * 8;
  const bf16_t* gK2 = gK1 + 1024;
  const bf16_t* vbase = vt + ((long)(b * NH + h) * DV) * T_SEQ;
  const bf16_t* gV0 = vbase + (long)(tid >> 2) * T_SEQ + (tid & 3) * 8;
  const bf16_t* gV1 = gV0 + (long)64 * T_SEQ;
  const int kw = (tid >> 3) * KSTR + (tid & 7) * 8;  // padded K write slot

  bf16_t* pb1 = &pbuf[w][0][0];
  bf16_t* pb2 = &pbuf[w][1][0];
  const float sc = 0.125f * LOG2E;  // 1/sqrt(64) folded with log2(e)
  const float lam = lamp[h];
  // swizzled P read offset: row l16, group quad ^ (l16>>2)
  const int prd = l16 * 40 + ((quad ^ (l16 >> 2)) << 3);

  for (int phase = 0; phase < 2; ++phase) {
    const int qblk = phase == 0 ? (15 - p) : p;
    const int q0 = qblk * 64 + w * 16;

    // ---- Q fragments ----
    const bf16_t* qrow = proj + (bT + q0 + l16) * (long)NPROJ + h * 64;
    bf16x8 aq1[2], aq2[2];
    aq1[0] = *(const bf16x8*)(qrow + quad * 8);
    aq1[1] = *(const bf16x8*)(qrow + 32 + quad * 8);
    aq2[0] = *(const bf16x8*)(qrow + 1024 + quad * 8);
    aq2[1] = *(const bf16x8*)(qrow + 1024 + 32 + quad * 8);

    f32x4 O1[8] = {}, O2[8] = {};
    float m1[4], l1[4], m2[4], l2[4];
#pragma unroll
    for (int i = 0; i < 4; ++i) {
      m1[i] = -3.0e38f;
      m2[i] = -3.0e38f;
      l1[i] = 0.f;
      l2[i] = 0.f;
    }

    const int kend_blk = qblk * 64 + 64;
    const int kend_w = q0 + 16;

    // ---- prime the register pipeline with tile kt=0 ----
    bf16x8 rK1 = *(const bf16x8*)(gK1);
    bf16x8 rK2 = *(const bf16x8*)(gK2);
    bf16x8 rV0 = *(const bf16x8*)(gV0);
    bf16x8 rV1 = *(const bf16x8*)(gV1);

    for (int kt = 0; kt < kend_blk; kt += 32) {
      *(bf16x8*)(Ks1 + kw) = rK1;
      *(bf16x8*)(Ks2 + kw) = rK2;
      *(bf16x8*)(Vs + tid * 8) = rV0;
      *(bf16x8*)(Vs + 2048 + tid * 8) = rV1;
      __syncthreads();

      if (kt + 32 < kend_blk) {
        const long ko = (long)(kt + 32) * NPROJ;
        rK1 = *(const bf16x8*)(gK1 + ko);
        rK2 = *(const bf16x8*)(gK2 + ko);
        rV0 = *(const bf16x8*)(gV0 + kt + 32);
        rV1 = *(const bf16x8*)(gV1 + kt + 32);
      }

      if (kt < kend_w) {
        // ---- S = Q K^T ----
        f32x4 s1[2], s2[2];
#pragma unroll
        for (int c = 0; c < 2; ++c) {
          const bf16_t* kr1 = Ks1 + (c * 16 + l16) * KSTR;
          const bf16_t* kr2 = Ks2 + (c * 16 + l16) * KSTR;
          bf16x8 b10 = *(const bf16x8*)(kr1 + quad * 8);
          bf16x8 b11 = *(const bf16x8*)(kr1 + 32 + quad * 8);
          f32x4 z = {};
          z = __builtin_amdgcn_mfma_f32_16x16x32_bf16(aq1[0], b10, z, 0, 0, 0);
          z = __builtin_amdgcn_mfma_f32_16x16x32_bf16(aq1[1], b11, z, 0, 0, 0);
          s1[c] = z;
          bf16x8 b20 = *(const bf16x8*)(kr2 + quad * 8);
          bf16x8 b21 = *(const bf16x8*)(kr2 + 32 + quad * 8);
          f32x4 z2 = {};
          z2 = __builtin_amdgcn_mfma_f32_16x16x32_bf16(aq2[0], b20, z2, 0, 0, 0);
          z2 = __builtin_amdgcn_mfma_f32_16x16x32_bf16(aq2[1], b21, z2, 0, 0, 0);
          s2[c] = z2;
        }
        // ---- scale + causal mask ----
        const bool need_mask = (kt + 31 > q0);
        float t1[2][4], t2[2][4], mx1[4], mx2[4];
#pragma unroll
        for (int i = 0; i < 4; ++i) {
          mx1[i] = -3.0e38f;
          mx2[i] = -3.0e38f;
        }
#pragma unroll
        for (int c = 0; c < 2; ++c) {
          const int col = kt + c * 16 + l16;
#pragma unroll
          for (int i = 0; i < 4; ++i) {
            const int row = q0 + quad * 4 + i;
            float v1 = s1[c][i] * sc, v2 = s2[c][i] * sc;
            if (need_mask && col > row) {
              v1 = -1e30f;
              v2 = -1e30f;
            }
            t1[c][i] = v1;
            t2[c][i] = v2;
            mx1[i] = fmaxf(mx1[i], v1);
            mx2[i] = fmaxf(mx2[i], v2);
          }
        }
#pragma unroll
        for (int i = 0; i < 4; ++i) {
          mx1[i] = row16_max(mx1[i]);
          mx2[i] = row16_max(mx2[i]);
        }
        float al1[4], al2[4];
#pragma unroll
        for (int i = 0; i < 4; ++i) {
          float mn = fmaxf(m1[i], mx1[i]);
          al1[i] = exp2f(m1[i] - mn);
          m1[i] = mn;
          mn = fmaxf(m2[i], mx2[i]);
          al2[i] = exp2f(m2[i] - mn);
          m2[i] = mn;
        }
        // ---- P = exp2(t - m) -> swizzled LDS (C->A layout transform) ----
        float sum1[4] = {0, 0, 0, 0}, sum2[4] = {0, 0, 0, 0};
#pragma unroll
        for (int c = 0; c < 2; ++c) {
          const int grp0 = c * 2 + (l16 >> 3);  // logical 8-elem group
#pragma unroll
          for (int i = 0; i < 4; ++i) {
            bf16_t p1 = (bf16_t)exp2f(t1[c][i] - m1[i]);
            bf16_t p2 = (bf16_t)exp2f(t2[c][i] - m2[i]);
            const int off =
                (quad * 4 + i) * 40 + ((grp0 ^ quad) << 3) + (l16 & 7);
            pb1[off] = p1;
            pb2[off] = p2;
            sum1[i] += (float)p1;
            sum2[i] += (float)p2;
          }
        }
#pragma unroll
        for (int i = 0; i < 4; ++i) {
          sum1[i] = row16_sum(sum1[i]);
          sum2[i] = row16_sum(sum2[i]);
        }
#pragma unroll
        for (int i = 0; i < 4; ++i) {
          l1[i] = l1[i] * al1[i] + sum1[i];
          l2[i] = l2[i] * al2[i] + sum2[i];
        }
#pragma unroll
        for (int f = 0; f < 8; ++f)
#pragma unroll
          for (int i = 0; i < 4; ++i) {
            O1[f][i] *= al1[i];
            O2[f][i] *= al2[i];
          }
        __asm__ volatile("s_waitcnt lgkmcnt(0)" ::: "memory");
        bf16x8 ap1 = *(const bf16x8*)(pb1 + prd);
        bf16x8 ap2 = *(const bf16x8*)(pb2 + prd);
        // ---- PV: O += P @ V ----
#pragma unroll
        for (int f = 0; f < 8; ++f) {
          bf16x8 bv = *(const bf16x8*)(Vs + (f * 16 + l16) * 32 + quad * 8);
          O1[f] =
              __builtin_amdgcn_mfma_f32_16x16x32_bf16(ap1, bv, O1[f], 0, 0, 0);
          O2[f] =
              __builtin_amdgcn_mfma_f32_16x16x32_bf16(ap2, bv, O2[f], 0, 0, 0);
        }
      }
      __syncthreads();
    }

    // ---- combine streams, subLN over 128 dims, scale, store bf16 ----
    float inv1[4], inv2[4];
#pragma unroll
    for (int i = 0; i < 4; ++i) {
      inv1[i] = 1.0f / l1[i];
      inv2[i] = lam / l2[i];
    }
    float sm[4], sq[4];
#pragma unroll
    for (int i = 0; i < 4; ++i) {
      sm[i] = 0.f;
      sq[i] = 0.f;
    }
#pragma unroll
    for (int f = 0; f < 8; ++f)
#pragma unroll
      for (int i = 0; i < 4; ++i) {
        float y = O1[f][i] * inv1[i] - O2[f][i] * inv2[i];
        O1[f][i] = y;
        sm[i] += y;
        sq[i] += y * y;
      }
#pragma unroll
    for (int i = 0; i < 4; ++i) {
      sm[i] = row16_sum(sm[i]);
      sq[i] = row16_sum(sq[i]);
    }
    float mu[4], rs[4];
#pragma unroll
    for (int i = 0; i < 4; ++i) {
      mu[i] = sm[i] * (1.0f / 128.0f);
      float var = sq[i] * (1.0f / 128.0f) - mu[i] * mu[i];
      rs[i] = rsqrtf(var + 1e-5f) * ONE_MINUS_LI;
    }
#pragma unroll
    for (int i = 0; i < 4; ++i) {
      bf16_t* dst = yln + (bT + q0 + quad * 4 + i) * (long)2048 + h * 128 + l16;
#pragma unroll
      for (int f = 0; f < 8; ++f)
        dst[f * 16] = (bf16_t)((O1[f][i] - mu[i]) * rs[i]);
    }
  }
}

// ---------------------------------------------------------------------------
extern "C" void kernel_launch(void* const* d_in, const int* in_sizes, int n_in,
                              void* d_out, int out_size, void* d_ws,
                              size_t ws_size, hipStream_t stream) {
  const float* x = (const float*)d_in[0];
  const float* Wq1 = (const float*)d_in[1];
  const float* Wq2 = (const float*)d_in[2];
  const float* Wk1 = (const float*)d_in[3];
  const float* Wk2 = (const float*)d_in[4];
  const float* Wv = (const float*)d_in[5];
  const float* Wc = (const float*)d_in[6];
  const float* lq1 = (const float*)d_in[7];
  const float* lk1 = (const float*)d_in[8];
  const float* lq2 = (const float*)d_in[9];
  const float* lk2 = (const float*)d_in[10];
  float* out = (float*)d_out;

  char* ws = (char*)d_ws;
  bf16_t* wcat = (bf16_t*)(ws + OFF_WCAT);
  bf16_t* xb = (bf16_t*)(ws + OFF_XB);
  bf16_t* wct = (bf16_t*)(ws + OFF_WCT);
  bf16_t* projb = (bf16_t*)(ws + OFF_PROJ);
  bf16_t* vtb = (bf16_t*)(ws + OFF_VT);
  bf16_t* ylnb = (bf16_t*)(ws + OFF_YLN);
  float* lamp = (float*)(ws + OFF_LAM);

  cast_x<<<4096, 256, 0, stream>>>(x, xb);
  tcast_w4<<<dim3(32, 32, 4), 256, 0, stream>>>(Wq1, Wq2, Wk1, Wk2, wcat);
  tcast_w<<<dim3(32, 64), 256, 0, stream>>>(Wv, wcat, 1024, 2048, 4096);
  tcast_w<<<dim3(64, 32), 256, 0, stream>>>(Wc, wct, 2048, 1024, 0);
  lam_kernel<<<1, 64, 0, stream>>>(lq1, lk1, lq2, lk2, lamp);

  // proj = xb @ wcat^T : M=4096 N=6144 K=1024
  gemm_bt<bf16_t><<<dim3(48, 32), 256, 0, stream>>>(xb, wcat, projb, 4096, 6144, 1024);
  transpose_v<<<dim3(32, 4, 64), 256, 0, stream>>>(projb, vtb);
  attn_kernel<<<dim3(8, 16, 4), 256, 0, stream>>>(projb, vtb, lamp, ylnb);
  // out = yln @ wc^T : M=4096 N=1024 K=2048
  gemm_bt<float><<<dim3(8, 32), 256, 0, stream>>>(ylnb, wct, out, 4096, 1024, 2048);
}

// Round 7
// 339.966 us; speedup vs baseline: 1.4867x; 1.0832x over previous
//
#include <hip/hip_runtime.h>

// ---------------------------------------------------------------------------
// DiffAttention forward, bf16 MFMA pipeline.  B=4 T=1024 C=1024 H=16 hs=64 dv=128.
//   1. cast x -> bf16; transpose-cast weights -> W^T[n][k] bf16
//   2. proj GEMM (m97-style global_load_lds): proj[4096][6144] = xb @ wcat^T
//   3. transpose v slice -> vt[(b,h)][dim][token]
//   4. attention: paired qblk (j & 15-j) x 64-KEY tiles, XCD-aware block
//      mapping (all 8 same-(h,b) blocks -> one XCD for L2 K/V reuse),
//      reg->LDS staged, online dual softmax, DPP row16 reductions,
//      XOR-swizzled P buffer, fused subLN
//   5. out GEMM: out[4096][1024] fp32 = yln @ wc^T
// MFMA mappings (HW-verified): A[m=lane&15][k=quad*8+j]; B^T[n=lane&15][k=...]
// C/D: col=lane&15, row=quad*4+reg.
// ---------------------------------------------------------------------------

#define T_SEQ 1024
#define NH 16
#define DV 128
#define NPROJ 6144
#define KSTR 72  // K/V/P LDS row stride (elements): 36 words == 4 mod 32

typedef __bf16 bf16_t;
typedef __bf16 bf16x8 __attribute__((ext_vector_type(8)));
typedef __bf16 bf16x4 __attribute__((ext_vector_type(4)));
typedef float f32x4 __attribute__((ext_vector_type(4)));

#define LAMBDA_INIT 0.35550906759096928f
#define ONE_MINUS_LI 0.6444909324090307f
#define LOG2E 1.4426950408889634f

// async global->LDS, 16B/lane (gemm only).
#define GLDS(g, l)                                                            \
  __builtin_amdgcn_global_load_lds(                                           \
      (const __attribute__((address_space(1))) void*)(g),                     \
      (__attribute__((address_space(3))) void*)(l), 16, 0, 0)

// ---- DPP 16-lane reductions (groups == DPP rows of 16) ----
template <int C>
__device__ __forceinline__ float dppf(float x) {
  return __builtin_bit_cast(
      float, __builtin_amdgcn_update_dpp(0, __builtin_bit_cast(int, x), C,
                                         0xF, 0xF, true));
}
__device__ __forceinline__ float row16_max(float x) {
  x = fmaxf(x, dppf<0xB1>(x));   // quad_perm xor1
  x = fmaxf(x, dppf<0x4E>(x));   // quad_perm xor2
  x = fmaxf(x, dppf<0x124>(x));  // row_ror:4
  x = fmaxf(x, dppf<0x128>(x));  // row_ror:8
  return x;
}
__device__ __forceinline__ float row16_sum(float x) {
  x += dppf<0xB1>(x);
  x += dppf<0x4E>(x);
  x += dppf<0x124>(x);
  x += dppf<0x128>(x);
  return x;
}

// ---------------- workspace layout (bytes) ----------------
static const size_t OFF_WCAT = 0;                                  // 6144x1024 bf16
static const size_t OFF_XB = OFF_WCAT + (size_t)6144 * 1024 * 2;   // 4096x1024 bf16
static const size_t OFF_WCT = OFF_XB + (size_t)4096 * 1024 * 2;    // 1024x2048 bf16
static const size_t OFF_PROJ = OFF_WCT + (size_t)2048 * 1024 * 2;  // 4096x6144 bf16
static const size_t OFF_VT = OFF_PROJ + (size_t)4096 * 6144 * 2;   // 64*128*1024 bf16
static const size_t OFF_YLN = OFF_VT + (size_t)64 * 128 * 1024 * 2;// 4096x2048 bf16
static const size_t OFF_LAM = OFF_YLN + (size_t)4096 * 2048 * 2;   // 16 f32

// ---------------- elementwise cast x -> bf16 ----------------
__global__ void __launch_bounds__(256) cast_x(const float* __restrict__ x,
                                              bf16_t* __restrict__ o) {
  const int i = (blockIdx.x * 256 + threadIdx.x) * 4;
  float4 v = *(const float4*)(x + i);
  bf16x4 r = {(bf16_t)v.x, (bf16_t)v.y, (bf16_t)v.z, (bf16_t)v.w};
  *(bf16x4*)(o + i) = r;
}

// ---------------- transpose-cast weight W[K][N] fp32 -> Wt[row0+n][k] bf16 ----
__device__ __forceinline__ void tcast_body(const float* __restrict__ W,
                                           bf16_t* __restrict__ Wt, int K,
                                           int N, int row0) {
  __shared__ float tile[32][33];
  const int k0 = blockIdx.x * 32, n0 = blockIdx.y * 32;
  const int tx = threadIdx.x & 31, ty = threadIdx.x >> 5;  // 32x8
#pragma unroll
  for (int i = 0; i < 32; i += 8)
    tile[ty + i][tx] = W[(long)(k0 + ty + i) * N + n0 + tx];
  __syncthreads();
#pragma unroll
  for (int i = 0; i < 32; i += 8)
    Wt[(long)(row0 + n0 + ty + i) * K + k0 + tx] = (bf16_t)tile[tx][ty + i];
}

__global__ void __launch_bounds__(256) tcast_w(const float* __restrict__ W,
                                               bf16_t* __restrict__ Wt, int K,
                                               int N, int row0) {
  tcast_body(W, Wt, K, N, row0);
}

// fused: the four 1024x1024 q/k weights in one launch (z selects)
__global__ void __launch_bounds__(256) tcast_w4(const float* __restrict__ W0,
                                                const float* __restrict__ W1,
                                                const float* __restrict__ W2,
                                                const float* __restrict__ W3,
                                                bf16_t* __restrict__ Wt) {
  const float* Ws[4] = {W0, W1, W2, W3};
  tcast_body(Ws[blockIdx.z], Wt, 1024, 1024, blockIdx.z * 1024);
}

// ---------------- per-head lambda ----------------
__global__ void lam_kernel(const float* __restrict__ lq1,
                           const float* __restrict__ lk1,
                           const float* __restrict__ lq2,
                           const float* __restrict__ lk2,
                           float* __restrict__ lam) {
  const int h = threadIdx.x;
  if (h < NH) {
    float d1 = 0.f, d2 = 0.f;
    for (int i = 0; i < 64; ++i) {
      d1 += lq1[h * 64 + i] * lk1[h * 64 + i];
      d2 += lq2[h * 64 + i] * lk2[h * 64 + i];
    }
    lam[h] = expf(d1) - expf(d2) + LAMBDA_INIT;
  }
}

// ---------------- GEMM (m97 structure): C[M][N] = A[M][K] @ Bt[N][K]^T -------
#define BM 128
#define BN 128
#define BK 32

template <typename OutT>
__global__ void __launch_bounds__(256) gemm_bt(const bf16_t* __restrict__ A,
                                               const bf16_t* __restrict__ Bt,
                                               OutT* __restrict__ C, int M,
                                               int N, int K) {
  __shared__ __align__(16) bf16_t As[BM * BK];
  __shared__ __align__(16) bf16_t Bs[BN * BK];
  const int tid = threadIdx.x;
  const int w = tid >> 6;
  const int lane = tid & 63;
  const int quad = lane >> 4, l16 = lane & 15;
  const int m0 = blockIdx.y * BM, n0 = blockIdx.x * BN;
  const int wm = (w >> 1) * 64, wn = (w & 1) * 64;
  const int srow = tid >> 2;       // 0..63
  const int scol = (tid & 3) * 8;  // 0,8,16,24

  const bf16_t* Ag0 = A + (long)(m0 + srow) * K + scol;
  const bf16_t* Ag1 = Ag0 + (long)64 * K;
  const bf16_t* Bg0 = Bt + (long)(n0 + srow) * K + scol;
  const bf16_t* Bg1 = Bg0 + (long)64 * K;
  bf16_t* lA0 = As + tid * 8;  // == srow*32 + scol
  bf16_t* lA1 = As + 2048 + tid * 8;
  bf16_t* lB0 = Bs + tid * 8;
  bf16_t* lB1 = Bs + 2048 + tid * 8;

  f32x4 acc[4][4] = {};

  for (int k0 = 0; k0 < K; k0 += BK) {
    GLDS(Ag0 + k0, lA0);
    GLDS(Ag1 + k0, lA1);
    GLDS(Bg0 + k0, lB0);
    GLDS(Bg1 + k0, lB1);
    __syncthreads();
    bf16x8 af[4], bfr[4];
#pragma unroll
    for (int t = 0; t < 4; ++t) {
      af[t] = *(const bf16x8*)(As + (wm + t * 16 + l16) * BK + quad * 8);
      bfr[t] = *(const bf16x8*)(Bs + (wn + t * 16 + l16) * BK + quad * 8);
    }
#pragma unroll
    for (int mt = 0; mt < 4; ++mt)
#pragma unroll
      for (int nt = 0; nt < 4; ++nt)
        acc[mt][nt] = __builtin_amdgcn_mfma_f32_16x16x32_bf16(
            af[mt], bfr[nt], acc[mt][nt], 0, 0, 0);
    __syncthreads();
  }

#pragma unroll
  for (int mt = 0; mt < 4; ++mt)
#pragma unroll
    for (int nt = 0; nt < 4; ++nt) {
      const int col = n0 + wn + nt * 16 + l16;
#pragma unroll
      for (int i = 0; i < 4; ++i) {
        const int row = m0 + wm + mt * 16 + quad * 4 + i;
        C[(long)row * N + col] = (OutT)acc[mt][nt][i];
      }
    }
}

// ---------------- transpose v slice of proj -> vt[(b,h)][d][t] ----------------
__global__ void __launch_bounds__(256) transpose_v(const bf16_t* __restrict__ proj,
                                                   bf16_t* __restrict__ vt) {
  __shared__ bf16_t tile[32][34];
  const int bh = blockIdx.z;
  const int b = bh >> 4, h = bh & 15;
  const int t0 = blockIdx.x * 32, d0 = blockIdx.y * 32;
  const int tx = threadIdx.x & 31, ty = threadIdx.x >> 5;
  const bf16_t* src = proj + (long)(b * T_SEQ) * NPROJ + 4096 + h * 128;
#pragma unroll
  for (int i = 0; i < 32; i += 8)
    tile[ty + i][tx] = src[(long)(t0 + ty + i) * NPROJ + d0 + tx];
  __syncthreads();
  bf16_t* dst = vt + ((long)(b * NH + h) * DV) * T_SEQ;
#pragma unroll
  for (int i = 0; i < 32; i += 8)
    dst[(long)(d0 + ty + i) * T_SEQ + t0 + tx] = tile[tx][ty + i];
}

// ---------------- attention: paired-qblk, 64-key tiles, XCD-mapped ---------
// grid: (128, B). x encodes p = x>>4 (0..7), h = x&15: all 8 same-(h,b)
// blocks share linear%8 -> same XCD -> K/V L2 reuse. Block p runs qblk 15-p
// then p (uniform 17 x 64-key staging iters). 4 waves; wave w owns q rows
// q0..q0+15. P buffer XOR-swizzled (8-elem group ^= row>>2), stride 72.
__global__ void __launch_bounds__(256) attn_kernel(const bf16_t* __restrict__ proj,
                                                   const bf16_t* __restrict__ vt,
                                                   const float* __restrict__ lamp,
                                                   bf16_t* __restrict__ yln) {
  const int p = blockIdx.x >> 4;  // 0..7
  const int h = blockIdx.x & 15;
  const int b = blockIdx.y;
  const int tid = threadIdx.x;
  const int w = tid >> 6, lane = tid & 63;
  const int quad = lane >> 4, l16 = lane & 15;
  const long bT = (long)b * T_SEQ;

  __shared__ __align__(16) bf16_t Ks1[64 * KSTR];  // [key][dim]
  __shared__ __align__(16) bf16_t Ks2[64 * KSTR];
  __shared__ __align__(16) bf16_t Vs[DV * KSTR];   // [dim][key]
  __shared__ __align__(16) bf16_t pbuf[4][2][16 * KSTR];

  // ---- staging source pointers (qblk-independent) ----
  const bf16_t* gK1 =
      proj + (bT + (tid >> 3)) * (long)NPROJ + h * 64 + 2048 + (tid & 7) * 8;
  const bf16_t* gK2 = gK1 + 1024;
  const bf16_t* vbase = vt + ((long)(b * NH + h) * DV) * T_SEQ;
  const bf16_t* gV = vbase + (long)(tid >> 3) * T_SEQ + (tid & 7) * 8;
  const int kw0 = (tid >> 3) * KSTR + (tid & 7) * 8;  // rows 0..31; +32*KSTR

  bf16_t* pb1 = &pbuf[w][0][0];
  bf16_t* pb2 = &pbuf[w][1][0];
  const float sc = 0.125f * LOG2E;  // 1/sqrt(64) folded with log2(e)
  const float lam = lamp[h];
  // swizzled P read offsets (row l16, logical group kc*4+quad)
  const int prd0 = l16 * KSTR + (((quad) ^ (l16 >> 2)) << 3);
  const int prd1 = l16 * KSTR + (((4 + quad) ^ (l16 >> 2)) << 3);

  for (int phase = 0; phase < 2; ++phase) {
    const int qblk = phase == 0 ? (15 - p) : p;
    const int q0 = qblk * 64 + w * 16;

    // ---- Q fragments ----
    const bf16_t* qrow = proj + (bT + q0 + l16) * (long)NPROJ + h * 64;
    bf16x8 aq1[2], aq2[2];
    aq1[0] = *(const bf16x8*)(qrow + quad * 8);
    aq1[1] = *(const bf16x8*)(qrow + 32 + quad * 8);
    aq2[0] = *(const bf16x8*)(qrow + 1024 + quad * 8);
    aq2[1] = *(const bf16x8*)(qrow + 1024 + 32 + quad * 8);

    f32x4 O1[8] = {}, O2[8] = {};
    float m1[4], l1[4], m2[4], l2[4];
#pragma unroll
    for (int i = 0; i < 4; ++i) {
      m1[i] = -3.0e38f;
      m2[i] = -3.0e38f;
      l1[i] = 0.f;
      l2[i] = 0.f;
    }

    const int kend_blk = qblk * 64 + 64;
    const int kend_w = q0 + 16;

    // ---- prime the register pipeline with tile kt=0 ----
    bf16x8 rK1[2], rK2[2], rV[4];
    rK1[0] = *(const bf16x8*)(gK1);
    rK1[1] = *(const bf16x8*)(gK1 + (long)32 * NPROJ);
    rK2[0] = *(const bf16x8*)(gK2);
    rK2[1] = *(const bf16x8*)(gK2 + (long)32 * NPROJ);
#pragma unroll
    for (int j = 0; j < 4; ++j)
      rV[j] = *(const bf16x8*)(gV + (long)(32 * j) * T_SEQ);

    for (int kt = 0; kt < kend_blk; kt += 64) {
      // ---- commit staged registers to LDS ----
      *(bf16x8*)(Ks1 + kw0) = rK1[0];
      *(bf16x8*)(Ks1 + kw0 + 32 * KSTR) = rK1[1];
      *(bf16x8*)(Ks2 + kw0) = rK2[0];
      *(bf16x8*)(Ks2 + kw0 + 32 * KSTR) = rK2[1];
#pragma unroll
      for (int j = 0; j < 4; ++j)
        *(bf16x8*)(Vs + kw0 + j * 32 * KSTR) = rV[j];
      __syncthreads();

      // ---- prefetch next tile into registers (overlaps compute) ----
      if (kt + 64 < kend_blk) {
        const long ko = (long)(kt + 64) * NPROJ;
        rK1[0] = *(const bf16x8*)(gK1 + ko);
        rK1[1] = *(const bf16x8*)(gK1 + ko + (long)32 * NPROJ);
        rK2[0] = *(const bf16x8*)(gK2 + ko);
        rK2[1] = *(const bf16x8*)(gK2 + ko + (long)32 * NPROJ);
#pragma unroll
        for (int j = 0; j < 4; ++j)
          rV[j] = *(const bf16x8*)(gV + kt + 64 + (long)(32 * j) * T_SEQ);
      }

      if (kt < kend_w) {
        // ---- S = Q K^T, 16x64 tile as 4 16x16 C-frags per stream ----
        f32x4 s1[4], s2[4];
#pragma unroll
        for (int c = 0; c < 4; ++c) {
          const bf16_t* kr1 = Ks1 + (c * 16 + l16) * KSTR;
          const bf16_t* kr2 = Ks2 + (c * 16 + l16) * KSTR;
          bf16x8 b10 = *(const bf16x8*)(kr1 + quad * 8);
          bf16x8 b11 = *(const bf16x8*)(kr1 + 32 + quad * 8);
          f32x4 z = {};
          z = __builtin_amdgcn_mfma_f32_16x16x32_bf16(aq1[0], b10, z, 0, 0, 0);
          z = __builtin_amdgcn_mfma_f32_16x16x32_bf16(aq1[1], b11, z, 0, 0, 0);
          s1[c] = z;
          bf16x8 b20 = *(const bf16x8*)(kr2 + quad * 8);
          bf16x8 b21 = *(const bf16x8*)(kr2 + 32 + quad * 8);
          f32x4 z2 = {};
          z2 = __builtin_amdgcn_mfma_f32_16x16x32_bf16(aq2[0], b20, z2, 0, 0, 0);
          z2 = __builtin_amdgcn_mfma_f32_16x16x32_bf16(aq2[1], b21, z2, 0, 0, 0);
          s2[c] = z2;
        }
        // ---- scale + causal mask (in place), track row max ----
        const bool need_mask = (kt + 63 > q0);
        float mx1[4], mx2[4];
#pragma unroll
        for (int i = 0; i < 4; ++i) {
          mx1[i] = -3.0e38f;
          mx2[i] = -3.0e38f;
        }
#pragma unroll
        for (int c = 0; c < 4; ++c) {
          const int col = kt + c * 16 + l16;
#pragma unroll
          for (int i = 0; i < 4; ++i) {
            const int row = q0 + quad * 4 + i;
            float v1 = s1[c][i] * sc, v2 = s2[c][i] * sc;
            if (need_mask && col > row) {
              v1 = -1e30f;
              v2 = -1e30f;
            }
            s1[c][i] = v1;
            s2[c][i] = v2;
            mx1[i] = fmaxf(mx1[i], v1);
            mx2[i] = fmaxf(mx2[i], v2);
          }
        }
#pragma unroll
        for (int i = 0; i < 4; ++i) {
          mx1[i] = row16_max(mx1[i]);
          mx2[i] = row16_max(mx2[i]);
        }
        float al1[4], al2[4];
#pragma unroll
        for (int i = 0; i < 4; ++i) {
          float mn = fmaxf(m1[i], mx1[i]);
          al1[i] = exp2f(m1[i] - mn);
          m1[i] = mn;
          mn = fmaxf(m2[i], mx2[i]);
          al2[i] = exp2f(m2[i] - mn);
          m2[i] = mn;
        }
        // ---- P = exp2(s - m) -> swizzled LDS (C->A layout transform) ----
        float sum1[4] = {0, 0, 0, 0}, sum2[4] = {0, 0, 0, 0};
#pragma unroll
        for (int c = 0; c < 4; ++c) {
          const int lg = c * 2 + (l16 >> 3);  // logical 8-elem group
#pragma unroll
          for (int i = 0; i < 4; ++i) {
            bf16_t p1 = (bf16_t)exp2f(s1[c][i] - m1[i]);
            bf16_t p2 = (bf16_t)exp2f(s2[c][i] - m2[i]);
            const int off =
                (quad * 4 + i) * KSTR + ((lg ^ quad) << 3) + (l16 & 7);
            pb1[off] = p1;
            pb2[off] = p2;
            sum1[i] += (float)p1;
            sum2[i] += (float)p2;
          }
        }
#pragma unroll
        for (int i = 0; i < 4; ++i) {
          sum1[i] = row16_sum(sum1[i]);
          sum2[i] = row16_sum(sum2[i]);
        }
#pragma unroll
        for (int i = 0; i < 4; ++i) {
          l1[i] = l1[i] * al1[i] + sum1[i];
          l2[i] = l2[i] * al2[i] + sum2[i];
        }
#pragma unroll
        for (int f = 0; f < 8; ++f)
#pragma unroll
          for (int i = 0; i < 4; ++i) {
            O1[f][i] *= al1[i];
            O2[f][i] *= al2[i];
          }
        __asm__ volatile("s_waitcnt lgkmcnt(0)" ::: "memory");
        bf16x8 ap1[2], ap2[2];
        ap1[0] = *(const bf16x8*)(pb1 + prd0);
        ap1[1] = *(const bf16x8*)(pb1 + prd1);
        ap2[0] = *(const bf16x8*)(pb2 + prd0);
        ap2[1] = *(const bf16x8*)(pb2 + prd1);
        // ---- PV: O += P @ V (two K=32 chunks) ----
#pragma unroll
        for (int f = 0; f < 8; ++f) {
          const bf16_t* vr = Vs + (f * 16 + l16) * KSTR;
          bf16x8 bv0 = *(const bf16x8*)(vr + quad * 8);
          bf16x8 bv1 = *(const bf16x8*)(vr + 32 + quad * 8);
          O1[f] =
              __builtin_amdgcn_mfma_f32_16x16x32_bf16(ap1[0], bv0, O1[f], 0, 0, 0);
          O1[f] =
              __builtin_amdgcn_mfma_f32_16x16x32_bf16(ap1[1], bv1, O1[f], 0, 0, 0);
          O2[f] =
              __builtin_amdgcn_mfma_f32_16x16x32_bf16(ap2[0], bv0, O2[f], 0, 0, 0);
          O2[f] =
              __builtin_amdgcn_mfma_f32_16x16x32_bf16(ap2[1], bv1, O2[f], 0, 0, 0);
        }
      }
      __syncthreads();
    }

    // ---- combine streams, subLN over 128 dims, scale, store bf16 ----
    float inv1[4], inv2[4];
#pragma unroll
    for (int i = 0; i < 4; ++i) {
      inv1[i] = 1.0f / l1[i];
      inv2[i] = lam / l2[i];
    }
    float sm[4], sq[4];
#pragma unroll
    for (int i = 0; i < 4; ++i) {
      sm[i] = 0.f;
      sq[i] = 0.f;
    }
#pragma unroll
    for (int f = 0; f < 8; ++f)
#pragma unroll
      for (int i = 0; i < 4; ++i) {
        float y = O1[f][i] * inv1[i] - O2[f][i] * inv2[i];
        O1[f][i] = y;
        sm[i] += y;
        sq[i] += y * y;
      }
#pragma unroll
    for (int i = 0; i < 4; ++i) {
      sm[i] = row16_sum(sm[i]);
      sq[i] = row16_sum(sq[i]);
    }
    float mu[4], rs[4];
#pragma unroll
    for (int i = 0; i < 4; ++i) {
      mu[i] = sm[i] * (1.0f / 128.0f);
      float var = sq[i] * (1.0f / 128.0f) - mu[i] * mu[i];
      rs[i] = rsqrtf(var + 1e-5f) * ONE_MINUS_LI;
    }
#pragma unroll
    for (int i = 0; i < 4; ++i) {
      bf16_t* dst = yln + (bT + q0 + quad * 4 + i) * (long)2048 + h * 128 + l16;
#pragma unroll
      for (int f = 0; f < 8; ++f)
        dst[f * 16] = (bf16_t)((O1[f][i] - mu[i]) * rs[i]);
    }
  }
}

// ---------------------------------------------------------------------------
extern "C" void kernel_launch(void* const* d_in, const int* in_sizes, int n_in,
                              void* d_out, int out_size, void* d_ws,
                              size_t ws_size, hipStream_t stream) {
  const float* x = (const float*)d_in[0];
  const float* Wq1 = (const float*)d_in[1];
  const float* Wq2 = (const float*)d_in[2];
  const float* Wk1 = (const float*)d_in[3];
  const float* Wk2 = (const float*)d_in[4];
  const float* Wv = (const float*)d_in[5];
  const float* Wc = (const float*)d_in[6];
  const float* lq1 = (const float*)d_in[7];
  const float* lk1 = (const float*)d_in[8];
  const float* lq2 = (const float*)d_in[9];
  const float* lk2 = (const float*)d_in[10];
  float* out = (float*)d_out;

  char* ws = (char*)d_ws;
  bf16_t* wcat = (bf16_t*)(ws + OFF_WCAT);
  bf16_t* xb = (bf16_t*)(ws + OFF_XB);
  bf16_t* wct = (bf16_t*)(ws + OFF_WCT);
  bf16_t* projb = (bf16_t*)(ws + OFF_PROJ);
  bf16_t* vtb = (bf16_t*)(ws + OFF_VT);
  bf16_t* ylnb = (bf16_t*)(ws + OFF_YLN);
  float* lamp = (float*)(ws + OFF_LAM);

  cast_x<<<4096, 256, 0, stream>>>(x, xb);
  tcast_w4<<<dim3(32, 32, 4), 256, 0, stream>>>(Wq1, Wq2, Wk1, Wk2, wcat);
  tcast_w<<<dim3(32, 64), 256, 0, stream>>>(Wv, wcat, 1024, 2048, 4096);
  tcast_w<<<dim3(64, 32), 256, 0, stream>>>(Wc, wct, 2048, 1024, 0);
  lam_kernel<<<1, 64, 0, stream>>>(lq1, lk1, lq2, lk2, lamp);

  // proj = xb @ wcat^T : M=4096 N=6144 K=1024
  gemm_bt<bf16_t><<<dim3(48, 32), 256, 0, stream>>>(xb, wcat, projb, 4096, 6144, 1024);
  transpose_v<<<dim3(32, 4, 64), 256, 0, stream>>>(projb, vtb);
  attn_kernel<<<dim3(128, 4), 256, 0, stream>>>(projb, vtb, lamp, ylnb);
  // out = yln @ wc^T : M=4096 N=1024 K=2048
  gemm_bt<float><<<dim3(8, 32), 256, 0, stream>>>(ylnb, wct, out, 4096, 1024, 2048);
}

// Round 9
// 335.496 us; speedup vs baseline: 1.5065x; 1.0133x over previous
//
#include <hip/hip_runtime.h>

// ---------------------------------------------------------------------------
// DiffAttention forward, bf16 MFMA pipeline.  B=4 T=1024 C=1024 H=16 hs=64 dv=128.
//   1. cast x -> bf16; transpose-cast weights -> W^T[n][k] bf16
//   2. proj GEMM (m97-style global_load_lds): proj[4096][6144] = xb @ wcat^T
//   3. transpose v slice -> vt[(b,h)][dim][token]
//   4. attention: TRANSPOSED-S chaining: S^T = K Q^T (16x16x32) so the P^T
//      C-frag [key=quad*4+reg][q=lane&15] feeds PV (O^T += V^T P^T, 16x16x16)
//      directly from registers -> NO P LDS round-trip. Softmax state per-lane
//      scalar (q = lane&15); reductions = in-lane + shfl_xor(16,32).
//      Paired qblk (j & 15-j), 64-key tiles, XCD-aware mapping, fused subLN.
//   5. out GEMM: out[4096][1024] fp32 = yln @ wc^T
// MFMA mappings (HW-verified): A[m=lane&15][k=quad*8+j] (K=32) / quad*4+j
// (K=16); B^T[n=lane&15][k=same]; C/D: col=lane&15, row=quad*4+reg.
// R8 lesson: the #error guard fired on the HOST pass (amdgcn builtins are
// invisible to __has_builtin there) — #else must be a host-safe dummy.
// ---------------------------------------------------------------------------

#define T_SEQ 1024
#define NH 16
#define DV 128
#define NPROJ 6144
#define KSTR 72  // K/V LDS row stride (elements)

typedef __bf16 bf16_t;
typedef __bf16 bf16x8 __attribute__((ext_vector_type(8)));
typedef __bf16 bf16x4 __attribute__((ext_vector_type(4)));
typedef short s16x4 __attribute__((ext_vector_type(4)));
typedef float f32x4 __attribute__((ext_vector_type(4)));

#define LAMBDA_INIT 0.35550906759096928f
#define ONE_MINUS_LI 0.6444909324090307f
#define LOG2E 1.4426950408889634f

// 16x16x16 bf16 MFMA (K=16). Device pass resolves a real builtin; the host
// pass (where __has_builtin is false for amdgcn builtins) gets a dummy that
// is never executed.
#if __has_builtin(__builtin_amdgcn_mfma_f32_16x16x16_bf16)
#define MFMA16(a, b, c) __builtin_amdgcn_mfma_f32_16x16x16_bf16(a, b, c, 0, 0, 0)
#elif __has_builtin(__builtin_amdgcn_mfma_f32_16x16x16bf16_1k)
#define MFMA16(a, b, c)                                                       \
  __builtin_amdgcn_mfma_f32_16x16x16bf16_1k(                                  \
      __builtin_bit_cast(s16x4, a), __builtin_bit_cast(s16x4, b), c, 0, 0, 0)
#else
#define MFMA16(a, b, c) (c)  // host pass only — never executed
#endif

// async global->LDS, 16B/lane (gemm only).
#define GLDS(g, l)                                                            \
  __builtin_amdgcn_global_load_lds(                                           \
      (const __attribute__((address_space(1))) void*)(g),                     \
      (__attribute__((address_space(3))) void*)(l), 16, 0, 0)

// ---------------- workspace layout (bytes) ----------------
static const size_t OFF_WCAT = 0;                                  // 6144x1024 bf16
static const size_t OFF_XB = OFF_WCAT + (size_t)6144 * 1024 * 2;   // 4096x1024 bf16
static const size_t OFF_WCT = OFF_XB + (size_t)4096 * 1024 * 2;    // 1024x2048 bf16
static const size_t OFF_PROJ = OFF_WCT + (size_t)2048 * 1024 * 2;  // 4096x6144 bf16
static const size_t OFF_VT = OFF_PROJ + (size_t)4096 * 6144 * 2;   // 64*128*1024 bf16
static const size_t OFF_YLN = OFF_VT + (size_t)64 * 128 * 1024 * 2;// 4096x2048 bf16
static const size_t OFF_LAM = OFF_YLN + (size_t)4096 * 2048 * 2;   // 16 f32

// ---------------- elementwise cast x -> bf16 ----------------
__global__ void __launch_bounds__(256) cast_x(const float* __restrict__ x,
                                              bf16_t* __restrict__ o) {
  const int i = (blockIdx.x * 256 + threadIdx.x) * 4;
  float4 v = *(const float4*)(x + i);
  bf16x4 r = {(bf16_t)v.x, (bf16_t)v.y, (bf16_t)v.z, (bf16_t)v.w};
  *(bf16x4*)(o + i) = r;
}

// ---------------- transpose-cast weight W[K][N] fp32 -> Wt[row0+n][k] bf16 ----
__device__ __forceinline__ void tcast_body(const float* __restrict__ W,
                                           bf16_t* __restrict__ Wt, int K,
                                           int N, int row0) {
  __shared__ float tile[32][33];
  const int k0 = blockIdx.x * 32, n0 = blockIdx.y * 32;
  const int tx = threadIdx.x & 31, ty = threadIdx.x >> 5;  // 32x8
#pragma unroll
  for (int i = 0; i < 32; i += 8)
    tile[ty + i][tx] = W[(long)(k0 + ty + i) * N + n0 + tx];
  __syncthreads();
#pragma unroll
  for (int i = 0; i < 32; i += 8)
    Wt[(long)(row0 + n0 + ty + i) * K + k0 + tx] = (bf16_t)tile[tx][ty + i];
}

__global__ void __launch_bounds__(256) tcast_w(const float* __restrict__ W,
                                               bf16_t* __restrict__ Wt, int K,
                                               int N, int row0) {
  tcast_body(W, Wt, K, N, row0);
}

// fused: the four 1024x1024 q/k weights in one launch (z selects)
__global__ void __launch_bounds__(256) tcast_w4(const float* __restrict__ W0,
                                                const float* __restrict__ W1,
                                                const float* __restrict__ W2,
                                                const float* __restrict__ W3,
                                                bf16_t* __restrict__ Wt) {
  const float* Ws[4] = {W0, W1, W2, W3};
  tcast_body(Ws[blockIdx.z], Wt, 1024, 1024, blockIdx.z * 1024);
}

// ---------------- per-head lambda ----------------
__global__ void lam_kernel(const float* __restrict__ lq1,
                           const float* __restrict__ lk1,
                           const float* __restrict__ lq2,
                           const float* __restrict__ lk2,
                           float* __restrict__ lam) {
  const int h = threadIdx.x;
  if (h < NH) {
    float d1 = 0.f, d2 = 0.f;
    for (int i = 0; i < 64; ++i) {
      d1 += lq1[h * 64 + i] * lk1[h * 64 + i];
      d2 += lq2[h * 64 + i] * lk2[h * 64 + i];
    }
    lam[h] = expf(d1) - expf(d2) + LAMBDA_INIT;
  }
}

// ---------------- GEMM (m97 structure): C[M][N] = A[M][K] @ Bt[N][K]^T -------
#define BM 128
#define BN 128
#define BK 32

template <typename OutT>
__global__ void __launch_bounds__(256) gemm_bt(const bf16_t* __restrict__ A,
                                               const bf16_t* __restrict__ Bt,
                                               OutT* __restrict__ C, int M,
                                               int N, int K) {
  __shared__ __align__(16) bf16_t As[BM * BK];
  __shared__ __align__(16) bf16_t Bs[BN * BK];
  const int tid = threadIdx.x;
  const int w = tid >> 6;
  const int lane = tid & 63;
  const int quad = lane >> 4, l16 = lane & 15;
  const int m0 = blockIdx.y * BM, n0 = blockIdx.x * BN;
  const int wm = (w >> 1) * 64, wn = (w & 1) * 64;
  const int srow = tid >> 2;       // 0..63
  const int scol = (tid & 3) * 8;  // 0,8,16,24

  const bf16_t* Ag0 = A + (long)(m0 + srow) * K + scol;
  const bf16_t* Ag1 = Ag0 + (long)64 * K;
  const bf16_t* Bg0 = Bt + (long)(n0 + srow) * K + scol;
  const bf16_t* Bg1 = Bg0 + (long)64 * K;
  bf16_t* lA0 = As + tid * 8;  // == srow*32 + scol
  bf16_t* lA1 = As + 2048 + tid * 8;
  bf16_t* lB0 = Bs + tid * 8;
  bf16_t* lB1 = Bs + 2048 + tid * 8;

  f32x4 acc[4][4] = {};

  for (int k0 = 0; k0 < K; k0 += BK) {
    GLDS(Ag0 + k0, lA0);
    GLDS(Ag1 + k0, lA1);
    GLDS(Bg0 + k0, lB0);
    GLDS(Bg1 + k0, lB1);
    __syncthreads();
    bf16x8 af[4], bfr[4];
#pragma unroll
    for (int t = 0; t < 4; ++t) {
      af[t] = *(const bf16x8*)(As + (wm + t * 16 + l16) * BK + quad * 8);
      bfr[t] = *(const bf16x8*)(Bs + (wn + t * 16 + l16) * BK + quad * 8);
    }
#pragma unroll
    for (int mt = 0; mt < 4; ++mt)
#pragma unroll
      for (int nt = 0; nt < 4; ++nt)
        acc[mt][nt] = __builtin_amdgcn_mfma_f32_16x16x32_bf16(
            af[mt], bfr[nt], acc[mt][nt], 0, 0, 0);
    __syncthreads();
  }

#pragma unroll
  for (int mt = 0; mt < 4; ++mt)
#pragma unroll
    for (int nt = 0; nt < 4; ++nt) {
      const int col = n0 + wn + nt * 16 + l16;
#pragma unroll
      for (int i = 0; i < 4; ++i) {
        const int row = m0 + wm + mt * 16 + quad * 4 + i;
        C[(long)row * N + col] = (OutT)acc[mt][nt][i];
      }
    }
}

// ---------------- transpose v slice of proj -> vt[(b,h)][d][t] ----------------
__global__ void __launch_bounds__(256) transpose_v(const bf16_t* __restrict__ proj,
                                                   bf16_t* __restrict__ vt) {
  __shared__ bf16_t tile[32][34];
  const int bh = blockIdx.z;
  const int b = bh >> 4, h = bh & 15;
  const int t0 = blockIdx.x * 32, d0 = blockIdx.y * 32;
  const int tx = threadIdx.x & 31, ty = threadIdx.x >> 5;
  const bf16_t* src = proj + (long)(b * T_SEQ) * NPROJ + 4096 + h * 128;
#pragma unroll
  for (int i = 0; i < 32; i += 8)
    tile[ty + i][tx] = src[(long)(t0 + ty + i) * NPROJ + d0 + tx];
  __syncthreads();
  bf16_t* dst = vt + ((long)(b * NH + h) * DV) * T_SEQ;
#pragma unroll
  for (int i = 0; i < 32; i += 8)
    dst[(long)(d0 + ty + i) * T_SEQ + t0 + tx] = tile[tx][ty + i];
}

// ---------------- attention: transposed-S, paired-qblk, 64-key tiles --------
// grid: (128, B). x encodes p = x>>4 (0..7), h = x&15 (same-(h,b) blocks ->
// one XCD for L2 K/V reuse). Block p runs qblk 15-p then p. 4 waves; wave w
// owns q rows q0..q0+15 (q = lane&15 for ALL its fragments).
__global__ void __launch_bounds__(256) attn_kernel(const bf16_t* __restrict__ proj,
                                                   const bf16_t* __restrict__ vt,
                                                   const float* __restrict__ lamp,
                                                   bf16_t* __restrict__ yln) {
  const int p = blockIdx.x >> 4;  // 0..7
  const int h = blockIdx.x & 15;
  const int b = blockIdx.y;
  const int tid = threadIdx.x;
  const int w = tid >> 6, lane = tid & 63;
  const int quad = lane >> 4, l16 = lane & 15;
  const long bT = (long)b * T_SEQ;

  __shared__ __align__(16) bf16_t Ks1[64 * KSTR];  // [key][dim]
  __shared__ __align__(16) bf16_t Ks2[64 * KSTR];
  __shared__ __align__(16) bf16_t Vs[DV * KSTR];   // [dim][key]

  // ---- staging source pointers (qblk-independent) ----
  const bf16_t* gK1 =
      proj + (bT + (tid >> 3)) * (long)NPROJ + h * 64 + 2048 + (tid & 7) * 8;
  const bf16_t* gK2 = gK1 + 1024;
  const bf16_t* vbase = vt + ((long)(b * NH + h) * DV) * T_SEQ;
  const bf16_t* gV = vbase + (long)(tid >> 3) * T_SEQ + (tid & 7) * 8;
  const int kw0 = (tid >> 3) * KSTR + (tid & 7) * 8;  // rows 0..31; +32*KSTR

  const float sc = 0.125f * LOG2E;  // 1/sqrt(64) folded with log2(e)
  const float lam = lamp[h];

  for (int phase = 0; phase < 2; ++phase) {
    const int qblk = phase == 0 ? (15 - p) : p;
    const int q0 = qblk * 64 + w * 16;
    const int qg = q0 + l16;  // this lane's q row (all fragments)

    // ---- Q fragments (B-operand role; same per-lane layout as A) ----
    const bf16_t* qrow = proj + (bT + qg) * (long)NPROJ + h * 64;
    bf16x8 aq1[2], aq2[2];
    aq1[0] = *(const bf16x8*)(qrow + quad * 8);
    aq1[1] = *(const bf16x8*)(qrow + 32 + quad * 8);
    aq2[0] = *(const bf16x8*)(qrow + 1024 + quad * 8);
    aq2[1] = *(const bf16x8*)(qrow + 1024 + 32 + quad * 8);

    f32x4 O1[8] = {}, O2[8] = {};  // O^T[d=f*16+quad*4+reg][q=l16]
    float m1 = -3.0e38f, m2 = -3.0e38f, l1 = 0.f, l2 = 0.f;

    const int kend_blk = qblk * 64 + 64;
    const int kend_w = q0 + 16;

    // ---- prime the register pipeline with tile kt=0 ----
    bf16x8 rK1[2], rK2[2], rV[4];
    rK1[0] = *(const bf16x8*)(gK1);
    rK1[1] = *(const bf16x8*)(gK1 + (long)32 * NPROJ);
    rK2[0] = *(const bf16x8*)(gK2);
    rK2[1] = *(const bf16x8*)(gK2 + (long)32 * NPROJ);
#pragma unroll
    for (int j = 0; j < 4; ++j)
      rV[j] = *(const bf16x8*)(gV + (long)(32 * j) * T_SEQ);

    for (int kt = 0; kt < kend_blk; kt += 64) {
      // ---- commit staged registers to LDS ----
      *(bf16x8*)(Ks1 + kw0) = rK1[0];
      *(bf16x8*)(Ks1 + kw0 + 32 * KSTR) = rK1[1];
      *(bf16x8*)(Ks2 + kw0) = rK2[0];
      *(bf16x8*)(Ks2 + kw0 + 32 * KSTR) = rK2[1];
#pragma unroll
      for (int j = 0; j < 4; ++j)
        *(bf16x8*)(Vs + kw0 + j * 32 * KSTR) = rV[j];
      __syncthreads();

      // ---- prefetch next tile into registers (overlaps compute) ----
      if (kt + 64 < kend_blk) {
        const long ko = (long)(kt + 64) * NPROJ;
        rK1[0] = *(const bf16x8*)(gK1 + ko);
        rK1[1] = *(const bf16x8*)(gK1 + ko + (long)32 * NPROJ);
        rK2[0] = *(const bf16x8*)(gK2 + ko);
        rK2[1] = *(const bf16x8*)(gK2 + ko + (long)32 * NPROJ);
#pragma unroll
        for (int j = 0; j < 4; ++j)
          rV[j] = *(const bf16x8*)(gV + kt + 64 + (long)(32 * j) * T_SEQ);
      }

      if (kt < kend_w) {
        // ---- S^T = K Q^T : A=K-frag (from LDS), B=Q-frag (regs) ----
        // S^T frag c: [key = kt+c*16+quad*4+reg][q = l16]
        f32x4 s1[4], s2[4];
#pragma unroll
        for (int c = 0; c < 4; ++c) {
          const bf16_t* kr1 = Ks1 + (c * 16 + l16) * KSTR;
          const bf16_t* kr2 = Ks2 + (c * 16 + l16) * KSTR;
          bf16x8 ka0 = *(const bf16x8*)(kr1 + quad * 8);
          bf16x8 ka1 = *(const bf16x8*)(kr1 + 32 + quad * 8);
          f32x4 z = {};
          z = __builtin_amdgcn_mfma_f32_16x16x32_bf16(ka0, aq1[0], z, 0, 0, 0);
          z = __builtin_amdgcn_mfma_f32_16x16x32_bf16(ka1, aq1[1], z, 0, 0, 0);
          s1[c] = z;
          bf16x8 kb0 = *(const bf16x8*)(kr2 + quad * 8);
          bf16x8 kb1 = *(const bf16x8*)(kr2 + 32 + quad * 8);
          f32x4 z2 = {};
          z2 = __builtin_amdgcn_mfma_f32_16x16x32_bf16(kb0, aq2[0], z2, 0, 0, 0);
          z2 = __builtin_amdgcn_mfma_f32_16x16x32_bf16(kb1, aq2[1], z2, 0, 0, 0);
          s2[c] = z2;
        }
        // ---- scale + causal mask, in-lane max over this lane's 16 keys ----
        const bool need_mask = (kt + 63 > q0);
        float mx1 = -3.0e38f, mx2 = -3.0e38f;
#pragma unroll
        for (int c = 0; c < 4; ++c) {
#pragma unroll
          for (int i = 0; i < 4; ++i) {
            const int key = kt + c * 16 + quad * 4 + i;
            float v1 = s1[c][i] * sc, v2 = s2[c][i] * sc;
            if (need_mask && key > qg) {
              v1 = -1e30f;
              v2 = -1e30f;
            }
            s1[c][i] = v1;
            s2[c][i] = v2;
            mx1 = fmaxf(mx1, v1);
            mx2 = fmaxf(mx2, v2);
          }
        }
        // cross-quad max (lanes sharing l16)
        mx1 = fmaxf(mx1, __shfl_xor(mx1, 16));
        mx1 = fmaxf(mx1, __shfl_xor(mx1, 32));
        mx2 = fmaxf(mx2, __shfl_xor(mx2, 16));
        mx2 = fmaxf(mx2, __shfl_xor(mx2, 32));
        const float mn1 = fmaxf(m1, mx1), mn2 = fmaxf(m2, mx2);
        const float al1 = exp2f(m1 - mn1), al2 = exp2f(m2 - mn2);
        m1 = mn1;
        m2 = mn2;
        // ---- P = exp2(s - m), packed bf16x4 per c (B-operand of PV) ----
        bf16x4 pc1[4], pc2[4];
        float sum1 = 0.f, sum2 = 0.f;
#pragma unroll
        for (int c = 0; c < 4; ++c) {
#pragma unroll
          for (int i = 0; i < 4; ++i) {
            bf16_t p1 = (bf16_t)exp2f(s1[c][i] - m1);
            bf16_t p2 = (bf16_t)exp2f(s2[c][i] - m2);
            pc1[c][i] = p1;
            pc2[c][i] = p2;
            sum1 += (float)p1;
            sum2 += (float)p2;
          }
        }
        sum1 += __shfl_xor(sum1, 16);
        sum1 += __shfl_xor(sum1, 32);
        sum2 += __shfl_xor(sum2, 16);
        sum2 += __shfl_xor(sum2, 32);
        l1 = l1 * al1 + sum1;
        l2 = l2 * al2 + sum2;
        // ---- rescale O accumulators (per-lane scalar alpha) ----
#pragma unroll
        for (int f = 0; f < 8; ++f)
#pragma unroll
          for (int i = 0; i < 4; ++i) {
            O1[f][i] *= al1;
            O2[f][i] *= al2;
          }
        // ---- PV: O^T += V^T P^T (16x16x16, P direct from regs) ----
#pragma unroll
        for (int c = 0; c < 4; ++c) {
#pragma unroll
          for (int f = 0; f < 8; ++f) {
            bf16x4 va =
                *(const bf16x4*)(Vs + (f * 16 + l16) * KSTR + c * 16 + quad * 4);
            O1[f] = MFMA16(va, pc1[c], O1[f]);
            O2[f] = MFMA16(va, pc2[c], O2[f]);
          }
        }
      }
      __syncthreads();
    }

    // ---- combine streams, subLN over 128 dims, scale, store bf16 ----
    const float inv1 = 1.0f / l1, inv2 = lam / l2;
    float sm = 0.f, sq = 0.f;
#pragma unroll
    for (int f = 0; f < 8; ++f)
#pragma unroll
      for (int i = 0; i < 4; ++i) {
        float y = O1[f][i] * inv1 - O2[f][i] * inv2;
        O1[f][i] = y;
        sm += y;
        sq += y * y;
      }
    sm += __shfl_xor(sm, 16);
    sm += __shfl_xor(sm, 32);
    sq += __shfl_xor(sq, 16);
    sq += __shfl_xor(sq, 32);
    const float mu = sm * (1.0f / 128.0f);
    const float var = sq * (1.0f / 128.0f) - mu * mu;
    const float rs = rsqrtf(var + 1e-5f) * ONE_MINUS_LI;
    bf16_t* dst = yln + (bT + qg) * (long)2048 + h * 128 + quad * 4;
#pragma unroll
    for (int f = 0; f < 8; ++f) {
      bf16x4 o = {(bf16_t)((O1[f][0] - mu) * rs), (bf16_t)((O1[f][1] - mu) * rs),
                  (bf16_t)((O1[f][2] - mu) * rs), (bf16_t)((O1[f][3] - mu) * rs)};
      *(bf16x4*)(dst + f * 16) = o;
    }
  }
}

// ---------------------------------------------------------------------------
extern "C" void kernel_launch(void* const* d_in, const int* in_sizes, int n_in,
                              void* d_out, int out_size, void* d_ws,
                              size_t ws_size, hipStream_t stream) {
  const float* x = (const float*)d_in[0];
  const float* Wq1 = (const float*)d_in[1];
  const float* Wq2 = (const float*)d_in[2];
  const float* Wk1 = (const float*)d_in[3];
  const float* Wk2 = (const float*)d_in[4];
  const float* Wv = (const float*)d_in[5];
  const float* Wc = (const float*)d_in[6];
  const float* lq1 = (const float*)d_in[7];
  const float* lk1 = (const float*)d_in[8];
  const float* lq2 = (const float*)d_in[9];
  const float* lk2 = (const float*)d_in[10];
  float* out = (float*)d_out;

  char* ws = (char*)d_ws;
  bf16_t* wcat = (bf16_t*)(ws + OFF_WCAT);
  bf16_t* xb = (bf16_t*)(ws + OFF_XB);
  bf16_t* wct = (bf16_t*)(ws + OFF_WCT);
  bf16_t* projb = (bf16_t*)(ws + OFF_PROJ);
  bf16_t* vtb = (bf16_t*)(ws + OFF_VT);
  bf16_t* ylnb = (bf16_t*)(ws + OFF_YLN);
  float* lamp = (float*)(ws + OFF_LAM);

  cast_x<<<4096, 256, 0, stream>>>(x, xb);
  tcast_w4<<<dim3(32, 32, 4), 256, 0, stream>>>(Wq1, Wq2, Wk1, Wk2, wcat);
  tcast_w<<<dim3(32, 64), 256, 0, stream>>>(Wv, wcat, 1024, 2048, 4096);
  tcast_w<<<dim3(64, 32), 256, 0, stream>>>(Wc, wct, 2048, 1024, 0);
  lam_kernel<<<1, 64, 0, stream>>>(lq1, lk1, lq2, lk2, lamp);

  // proj = xb @ wcat^T : M=4096 N=6144 K=1024
  gemm_bt<bf16_t><<<dim3(48, 32), 256, 0, stream>>>(xb, wcat, projb, 4096, 6144, 1024);
  transpose_v<<<dim3(32, 4, 64), 256, 0, stream>>>(projb, vtb);
  attn_kernel<<<dim3(128, 4), 256, 0, stream>>>(projb, vtb, lamp, ylnb);
  // out = yln @ wc^T : M=4096 N=1024 K=2048
  gemm_bt<float><<<dim3(8, 32), 256, 0, stream>>>(ylnb, wct, out, 4096, 1024, 2048);
}